// Round 8
// baseline (2918.500 us; speedup 1.0000x reference)
//
#include <hip/hip_runtime.h>
#include <stdint.h>

// ---------------------------------------------------------------------------
// PairwiseAttentionLinear — fp32 in/out on device.
// Round 8: gemm8 K-loop rebuilt as counted-lgkm CROSS-MFMA schedule:
// all 24 ds_reads issued at tile start (ordered), MFMA quadrants gated by
// LGKM(12)/LGKM(8)/LGKM(0) so reads drain UNDER the MFMAs; 3 barriers/tile
// (was 8). Staging hazards: B staged after all-waves B-reads-done barrier,
// A staged after all-waves A-reads-done barrier; VMC(8) = prev tile landed.
// ---------------------------------------------------------------------------

typedef __bf16 bf16x8 __attribute__((ext_vector_type(8)));
typedef float f32x4 __attribute__((ext_vector_type(4)));

static __device__ __forceinline__ float bf2f(unsigned short u) {
  unsigned int x = ((unsigned int)u) << 16;
  float f;
  __builtin_memcpy(&f, &x, 4);
  return f;
}
static __device__ __forceinline__ unsigned short f2bf(float f) {
  unsigned int x;
  __builtin_memcpy(&x, &f, 4);
  x += 0x7fffu + ((x >> 16) & 1u);  // RNE
  return (unsigned short)(x >> 16);
}

static __device__ __forceinline__ void gload_lds16(const void* g, void* l) {
  __builtin_amdgcn_global_load_lds(
      (const __attribute__((address_space(1))) unsigned int*)g,
      (__attribute__((address_space(3))) unsigned int*)l, 16, 0, 0);
}

__global__ __launch_bounds__(256) void cvt_kernel(
    const float* __restrict__ in, unsigned short* __restrict__ out, long n) {
  const long i = ((long)blockIdx.x * 256 + threadIdx.x) * 4;
  if (i + 3 < n) {
    float4 f = *(const float4*)(in + i);
    *(ushort4*)(out + i) = make_ushort4(f2bf(f.x), f2bf(f.y), f2bf(f.z), f2bf(f.w));
  }
}

// ---------------------------------------------------------------------------
// gemm8: 256x256 tile, BK=64, 512 thr (8 waves, 2Mx4N), per-wave 128x64.
// LDS 128 KiB dbuf, prefetch distance 2. T2 swizzle via pre-swizzled global
// source + swizzled ds_read. Counted-lgkm schedule (see header comment).
// ---------------------------------------------------------------------------
#define BARRIER __builtin_amdgcn_s_barrier()
#define LGKM(N)                                                     \
  do {                                                              \
    asm volatile("s_waitcnt lgkmcnt(" #N ")" ::: "memory");         \
    __builtin_amdgcn_sched_barrier(0);                              \
  } while (0)
#define VMC(N)                                                      \
  do {                                                              \
    asm volatile("s_waitcnt vmcnt(" #N ")" ::: "memory");           \
    __builtin_amdgcn_sched_barrier(0);                              \
  } while (0)

__global__ __launch_bounds__(512, 2) void gemm8_kernel(
    const unsigned short* __restrict__ A, int lda,
    const unsigned short* __restrict__ B, int K,
    void* __restrict__ Cp, int ldc, const float* __restrict__ bias,
    int relu, int out_f32, int resadd,
    const unsigned short* __restrict__ A2, const unsigned short* __restrict__ B2,
    void* __restrict__ C2p, const float* __restrict__ bias2, int dual) {
  extern __shared__ __align__(16) char smem[];  // 131072 B

  const int tid = threadIdx.x;
  const int lane = tid & 63;
  const int w = tid >> 6;
  const int wm = w >> 2;  // 0..1
  const int wn = w & 3;   // 0..3
  const long brow = (long)blockIdx.y * 256;

  const unsigned short* Ap = A;
  const unsigned short* Bp = B;
  const float* bi = bias;
  void* Cq = Cp;
  long bcol;
  if (dual && (int)blockIdx.x >= (int)(gridDim.x >> 1)) {
    Ap = A2; Bp = B2; bi = bias2; Cq = C2p;
    bcol = (long)(blockIdx.x - (gridDim.x >> 1)) * 256;
  } else {
    bcol = (long)blockIdx.x * 256;
  }

  const int NT = K >> 6;  // K-tiles of 64

  // ---- staging addressing, hoisted
  const int lrA = tid >> 3;
  const int scb = ((tid & 7) * 16) ^ (((tid >> 3) & 7) << 4);  // pre-swz src
  const unsigned wb = (unsigned)(tid & ~63) * 16;
  const long ldab = (long)lda * 2;
  const long ldbb = (long)K * 2;
  const char* gA = (const char*)Ap + (brow + lrA) * ldab + scb;
  const char* gB = (const char*)Bp + (bcol + lrA) * ldbb + scb;
  const long a64 = 64 * ldab, a128 = 128 * ldab, a192 = 192 * ldab;
  const long b64 = 64 * ldbb, b128 = 128 * ldbb, b192 = 192 * ldbb;

#define STAGE_A(bb, off)                                        \
  do {                                                          \
    gload_lds16(gA + (off), smem + (bb) + wb);                  \
    gload_lds16(gA + a64 + (off), smem + (bb) + 8192 + wb);     \
    gload_lds16(gA + a128 + (off), smem + (bb) + 16384 + wb);   \
    gload_lds16(gA + a192 + (off), smem + (bb) + 24576 + wb);   \
  } while (0)
#define STAGE_B(bb, off)                                        \
  do {                                                          \
    gload_lds16(gB + (off), smem + (bb) + 32768 + wb);          \
    gload_lds16(gB + b64 + (off), smem + (bb) + 40960 + wb);    \
    gload_lds16(gB + b128 + (off), smem + (bb) + 49152 + wb);   \
    gload_lds16(gB + b192 + (off), smem + (bb) + 57344 + wb);   \
  } while (0)

  f32x4 acc[8][4];
  const f32x4 fz = {0.f, 0.f, 0.f, 0.f};
#pragma unroll
  for (int m = 0; m < 8; ++m)
#pragma unroll
    for (int n = 0; n < 4; ++n) acc[m][n] = fz;

  const int frow = lane & 15;
  const int fkb = (lane >> 4) * 16;  // k-byte within 64-col row
  const int fswz = (lane & 7) << 4;  // T2 read-side swizzle

#define RDA(dst, CB, M, KK)                                                   \
  dst = *(const bf16x8*)(smem + (CB) + (wm * 128 + (M) * 16 + frow) * 128 +   \
                         (((KK) * 64 + fkb) ^ fswz))
#define RDB(dst, CB, N, KK)                                                   \
  dst = *(const bf16x8*)(smem + (CB) + 32768 +                                \
                         (wn * 64 + (N) * 16 + frow) * 128 +                  \
                         (((KK) * 64 + fkb) ^ fswz))

  // 8 MFMAs, kk outer (reuse distance 4)
#define MM8(AF, MA, BF, NA, MO, NO)                                           \
  do {                                                                        \
    _Pragma("unroll") for (int kk = 0; kk < 2; ++kk)                          \
    _Pragma("unroll") for (int mm = 0; mm < 2; ++mm)                          \
    _Pragma("unroll") for (int nn = 0; nn < 2; ++nn)                          \
        acc[(MO) + mm][(NO) + nn] = __builtin_amdgcn_mfma_f32_16x16x32_bf16(  \
            AF[(MA) + mm][kk], BF[(NA) + nn][kk], acc[(MO) + mm][(NO) + nn],  \
            0, 0, 0);                                                         \
  } while (0)
#define MM8N(AF, BF, NB, NO)                                                  \
  do {                                                                        \
    _Pragma("unroll") for (int kk = 0; kk < 2; ++kk)                          \
    _Pragma("unroll") for (int mm = 0; mm < 4; ++mm)                          \
        acc[mm][(NO)] = __builtin_amdgcn_mfma_f32_16x16x32_bf16(              \
            AF[mm][kk], BF[(NB)][kk], acc[mm][(NO)], 0, 0, 0);                \
  } while (0)

  bf16x8 afL[4][2], afH[4][2], bfvL[2][2], bfvH[2][2];

  // ---- prologue: stage tiles 0 (buf0) and 1 (buf1); wait tile 0
  STAGE_A(0, 0);
  STAGE_B(0, 0);
  STAGE_A(65536, 128);
  STAGE_B(65536, 128);
  VMC(8);
  BARRIER;
  long soff = 256;  // staging byte-offset of tile t+2

  // Counted-lgkm tile schedule. DS reads complete IN ORDER per wave, so
  // LGKM(N) gates exactly the first 24-N reads. Order: bfvL(4) afL(8)
  // bfvH(4) afH(8).
  //   LGKM(12) -> Q0 (needs #1-12)         [12 reads in flight under MFMA]
  //   LGKM(8)  -> all B-region reads done -> BARRIER -> STAGE_B ; Q1
  //   LGKM(0)  -> all A-region reads done -> BARRIER -> STAGE_A ; VMC(8) ;
  //               Q2 ; Q3 ; BARRIER (tile boundary)
#define TILE_IT(T, CB)                                                        \
  do {                                                                        \
    RDB(bfvL[0][0], CB, 0, 0); RDB(bfvL[0][1], CB, 0, 1);                     \
    RDB(bfvL[1][0], CB, 1, 0); RDB(bfvL[1][1], CB, 1, 1);                     \
    RDA(afL[0][0], CB, 0, 0); RDA(afL[0][1], CB, 0, 1);                       \
    RDA(afL[1][0], CB, 1, 0); RDA(afL[1][1], CB, 1, 1);                       \
    RDA(afL[2][0], CB, 2, 0); RDA(afL[2][1], CB, 2, 1);                       \
    RDA(afL[3][0], CB, 3, 0); RDA(afL[3][1], CB, 3, 1);                       \
    RDB(bfvH[0][0], CB, 2, 0); RDB(bfvH[0][1], CB, 2, 1);                     \
    RDB(bfvH[1][0], CB, 3, 0); RDB(bfvH[1][1], CB, 3, 1);                     \
    RDA(afH[0][0], CB, 4, 0); RDA(afH[0][1], CB, 4, 1);                       \
    RDA(afH[1][0], CB, 5, 0); RDA(afH[1][1], CB, 5, 1);                       \
    RDA(afH[2][0], CB, 6, 0); RDA(afH[2][1], CB, 6, 1);                       \
    RDA(afH[3][0], CB, 7, 0); RDA(afH[3][1], CB, 7, 1);                       \
    LGKM(12);                                                                 \
    __builtin_amdgcn_s_setprio(1);                                            \
    MM8(afL, 0, bfvL, 0, 0, 0);                                               \
    MM8(afL, 2, bfvL, 0, 2, 0); /* Q0 */                                      \
    LGKM(8);  /* B-region (bfvL+bfvH) complete for this wave */               \
    BARRIER;  /* ... for ALL waves -> B staging safe */                       \
    if ((T) + 2 < NT) STAGE_B(CB, soff);                                      \
    MM8N(afL, bfvH, 0, 2);                                                    \
    MM8N(afL, bfvH, 1, 3); /* Q1 */                                           \
    LGKM(0);  /* A-region complete for this wave */                           \
    BARRIER;  /* ... for ALL waves -> A staging safe */                       \
    if ((T) + 2 < NT) {                                                       \
      STAGE_A(CB, soff);                                                      \
      VMC(8); /* tile T+1 fully landed */                                     \
    } else {                                                                  \
      VMC(0); /* tail drain */                                                \
    }                                                                         \
    MM8(afH, 0, bfvL, 0, 4, 0);                                               \
    MM8(afH, 2, bfvL, 0, 6, 0); /* Q2 */                                      \
    MM8(afH, 0, bfvH, 0, 4, 2);                                               \
    MM8(afH, 2, bfvH, 0, 6, 2); /* Q3 */                                      \
    __builtin_amdgcn_s_setprio(0);                                            \
    BARRIER;  /* tile boundary */                                             \
    soff += 128;                                                              \
  } while (0)

  for (int t = 0; t < NT; t += 2) {
    TILE_IT(t, 0);
    TILE_IT(t + 1, 65536);
  }

  // ---- epilogue: C/D layout col=lane&15, row=(lane>>4)*4+reg [m89]
  const long rb0 = brow + wm * 128 + (lane >> 4) * 4;
  const long cb0 = bcol + wn * 64 + (lane & 15);
#pragma unroll
  for (int m = 0; m < 8; ++m) {
#pragma unroll
    for (int n = 0; n < 4; ++n) {
      const long col = cb0 + n * 16;
      const float bv = bi ? bi[col] : 0.f;
#pragma unroll
      for (int j = 0; j < 4; ++j) {
        const long r = rb0 + m * 16 + j;
        float v = acc[m][n][j] + bv;
        if (relu) v = fmaxf(v, 0.f);
        if (out_f32) {
          float* cp = (float*)Cq + r * (long)ldc + col;
          if (resadd) v += *cp;
          *cp = v;
        } else {
          ((unsigned short*)Cq)[r * (long)ldc + col] = f2bf(v);
        }
      }
    }
  }
#undef TILE_IT
#undef STAGE_A
#undef STAGE_B
#undef RDA
#undef RDB
#undef MM8
#undef MM8N
}

// ---------------------------------------------------------------------------
// Legacy 128x128 GEMM — fallback path only.
// ---------------------------------------------------------------------------
__global__ __launch_bounds__(256) void gemm_bt_kernel(
    const unsigned short* __restrict__ A, int lda,
    const unsigned short* __restrict__ B, int K,
    void* __restrict__ Cp, int ldc,
    const float* __restrict__ bias,
    const void* __restrict__ res, int res_mode, int ldres,
    int relu, int out_f32) {
  __shared__ __align__(16) unsigned short As[128 * 32];
  __shared__ __align__(16) unsigned short Bs[128 * 32];

  const int t = threadIdx.x;
  const int lane = t & 63;
  const int w = t >> 6;
  const int wr = (w >> 1) * 64;
  const int wc = (w & 1) * 64;
  const long brow = (long)blockIdx.y * 128;
  const long bcol = (long)blockIdx.x * 128;

  const int srow = lane >> 2;
  const int scol = (lane & 3) * 8;
  const unsigned short* Ab = A + (brow + w * 32 + srow) * (long)lda + scol;
  const unsigned short* Bb = B + (bcol + w * 32 + srow) * (long)K + scol;
  unsigned short* Asb = &As[(w * 32) * 32];
  unsigned short* Bsb = &Bs[(w * 32) * 32];

  f32x4 acc[4][4];
  const f32x4 fzero = {0.f, 0.f, 0.f, 0.f};
#pragma unroll
  for (int m = 0; m < 4; ++m)
#pragma unroll
    for (int n = 0; n < 4; ++n) acc[m][n] = fzero;

  const int fr = lane & 15;
  const int fk = (lane >> 4) * 8;

  for (int kt = 0; kt < K; kt += 32) {
    gload_lds16(Ab + kt, Asb);
    gload_lds16(Ab + 16 * (long)lda + kt, Asb + 16 * 32);
    gload_lds16(Bb + kt, Bsb);
    gload_lds16(Bb + 16 * (long)K + kt, Bsb + 16 * 32);
    __syncthreads();

    bf16x8 af[4], bfv[4];
#pragma unroll
    for (int m = 0; m < 4; ++m)
      af[m] = *(const bf16x8*)&As[(wr + m * 16 + fr) * 32 + fk];
#pragma unroll
    for (int n = 0; n < 4; ++n)
      bfv[n] = *(const bf16x8*)&Bs[(wc + n * 16 + fr) * 32 + fk];
#pragma unroll
    for (int m = 0; m < 4; ++m)
#pragma unroll
      for (int n = 0; n < 4; ++n)
        acc[m][n] = __builtin_amdgcn_mfma_f32_16x16x32_bf16(af[m], bfv[n],
                                                            acc[m][n], 0, 0, 0);
    __syncthreads();
  }

  const long rbase = brow + wr + (lane >> 4) * 4;
#pragma unroll
  for (int m = 0; m < 4; ++m) {
#pragma unroll
    for (int n = 0; n < 4; ++n) {
      const long col = bcol + wc + n * 16 + fr;
      const float bv = bias ? bias[col] : 0.f;
#pragma unroll
      for (int j = 0; j < 4; ++j) {
        const long r = rbase + m * 16 + j;
        float v = acc[m][n][j] + bv;
        if (relu) v = fmaxf(v, 0.f);
        if (res_mode == 1)
          v += ((const float*)res)[r * (long)ldres + col];
        else if (res_mode == 2)
          v += bf2f(((const unsigned short*)res)[r * (long)ldres + col]);
        if (out_f32)
          ((float*)Cp)[r * (long)ldc + col] = v;
        else
          ((unsigned short*)Cp)[r * (long)ldc + col] = f2bf(v);
      }
    }
  }
}

// ---------------------------------------------------------------------------
template <int L>
__global__ __launch_bounds__(256) void ln_kernel(
    const void* __restrict__ inp, int in_bf16, int ldin,
    const float* __restrict__ g, const float* __restrict__ b,
    unsigned short* __restrict__ outp, int ldout) {
  constexpr int VEC = L / 256;
  const long row = blockIdx.x;
  const int t = threadIdx.x;
  float v[VEC];
  if (in_bf16) {
    const unsigned short* p = (const unsigned short*)inp + row * (long)ldin + t * VEC;
#pragma unroll
    for (int i = 0; i < VEC; i += 4) {
      ushort4 u = *(const ushort4*)(p + i);
      v[i] = bf2f(u.x); v[i + 1] = bf2f(u.y); v[i + 2] = bf2f(u.z); v[i + 3] = bf2f(u.w);
    }
  } else {
    const float* p = (const float*)inp + row * (long)ldin + t * VEC;
#pragma unroll
    for (int i = 0; i < VEC; i += 4) {
      float4 f = *(const float4*)(p + i);
      v[i] = f.x; v[i + 1] = f.y; v[i + 2] = f.z; v[i + 3] = f.w;
    }
  }
  float s = 0.f, sq = 0.f;
#pragma unroll
  for (int i = 0; i < VEC; ++i) { s += v[i]; sq += v[i] * v[i]; }
#pragma unroll
  for (int off = 32; off; off >>= 1) {
    s += __shfl_xor(s, off, 64);
    sq += __shfl_xor(sq, off, 64);
  }
  __shared__ float red[8];
  if ((t & 63) == 0) { red[t >> 6] = s; red[4 + (t >> 6)] = sq; }
  __syncthreads();
  s = red[0] + red[1] + red[2] + red[3];
  sq = red[4] + red[5] + red[6] + red[7];
  const float mean = s * (1.f / L);
  const float var = sq * (1.f / L) - mean * mean;
  const float rstd = rsqrtf(var + 1e-6f);
  unsigned short* op = outp + row * (long)ldout + t * VEC;
  const float* gp = g + t * VEC;
  const float* bp = b + t * VEC;
#pragma unroll
  for (int i = 0; i < VEC; i += 4) {
    float4 gg = *(const float4*)(gp + i);
    float4 bb = *(const float4*)(bp + i);
    *(ushort4*)(op + i) = make_ushort4(
        f2bf((v[i + 0] - mean) * rstd * gg.x + bb.x),
        f2bf((v[i + 1] - mean) * rstd * gg.y + bb.y),
        f2bf((v[i + 2] - mean) * rstd * gg.z + bb.z),
        f2bf((v[i + 3] - mean) * rstd * gg.w + bb.w));
  }
}

// ---------------------------------------------------------------------------
// Pairwise attention glue + optional fused d/t LayerNorms.
// ---------------------------------------------------------------------------
__global__ __launch_bounds__(512) void attn_glue_kernel(
    const unsigned short* __restrict__ Q, const unsigned short* __restrict__ Kq,
    const unsigned short* __restrict__ V, int ld, const void* __restrict__ Xres,
    int res_bf16, void* __restrict__ Xout, int out_bf16,
    unsigned short* __restrict__ Xout_bf,
    unsigned short* __restrict__ DNp, unsigned short* __restrict__ TNp,
    const float* __restrict__ lnd_g, const float* __restrict__ lnd_b,
    const float* __restrict__ lnt_g, const float* __restrict__ lnt_b) {
  const long row = blockIdx.x;
  const int h = threadIdx.x >> 6;
  const int lane = threadIdx.x & 63;
  const long qbase = row * (long)ld + h * 256;
  const long xbase = row * 2048 + h * 256;
  const int d = lane * 2;

  ushort2 q0 = *(const ushort2*)&Q[qbase + d];
  ushort2 q1 = *(const ushort2*)&Q[qbase + 128 + d];
  ushort2 k0 = *(const ushort2*)&Kq[qbase + d];
  ushort2 k1 = *(const ushort2*)&Kq[qbase + 128 + d];
  ushort2 v0 = *(const ushort2*)&V[qbase + d];
  ushort2 v1 = *(const ushort2*)&V[qbase + 128 + d];

  const float q0x = bf2f(q0.x), q0y = bf2f(q0.y);
  const float q1x = bf2f(q1.x), q1y = bf2f(q1.y);
  const float k0x = bf2f(k0.x), k0y = bf2f(k0.y);
  const float k1x = bf2f(k1.x), k1y = bf2f(k1.y);

  float s00 = q0x * k0x + q0y * k0y;
  float s01 = q0x * k1x + q0y * k1y;
  float s10 = q1x * k0x + q1y * k0y;
  float s11 = q1x * k1x + q1y * k1y;
#pragma unroll
  for (int off = 32; off; off >>= 1) {
    s00 += __shfl_xor(s00, off, 64);
    s01 += __shfl_xor(s01, off, 64);
    s10 += __shfl_xor(s10, off, 64);
    s11 += __shfl_xor(s11, off, 64);
  }
  const float SC = 0.088388347648318447f;  // 1/sqrt(128)
  s00 *= SC; s01 *= SC; s10 *= SC; s11 *= SC;
  const float m0 = fmaxf(s00, s01), m1 = fmaxf(s10, s11);
  const float e00 = __expf(s00 - m0), e01 = __expf(s01 - m0);
  const float e10 = __expf(s10 - m1), e11 = __expf(s11 - m1);
  const float i0 = 1.f / (e00 + e01), i1 = 1.f / (e10 + e11);
  const float a00 = e00 * i0, a01 = e01 * i0;
  const float a10 = e10 * i1, a11 = e11 * i1;

  const float v0x = bf2f(v0.x), v0y = bf2f(v0.y);
  const float v1x = bf2f(v1.x), v1y = bf2f(v1.y);
  float o0x = a00 * v0x + a01 * v1x, o0y = a00 * v0y + a01 * v1y;
  float o1x = a10 * v0x + a11 * v1x, o1y = a10 * v0y + a11 * v1y;

  if (res_bf16) {
    const unsigned short* xr = (const unsigned short*)Xres + xbase;
    ushort2 ra = *(const ushort2*)&xr[d];
    ushort2 rb = *(const ushort2*)&xr[128 + d];
    o0x += bf2f(ra.x); o0y += bf2f(ra.y); o1x += bf2f(rb.x); o1y += bf2f(rb.y);
  } else {
    const float* xr = (const float*)Xres + xbase;
    float2 ra = *(const float2*)&xr[d];
    float2 rb = *(const float2*)&xr[128 + d];
    o0x += ra.x; o0y += ra.y; o1x += rb.x; o1y += rb.y;
  }
  if (out_bf16) {
    unsigned short* xo = (unsigned short*)Xout + xbase;
    *(ushort2*)&xo[d] = make_ushort2(f2bf(o0x), f2bf(o0y));
    *(ushort2*)&xo[128 + d] = make_ushort2(f2bf(o1x), f2bf(o1y));
  } else {
    float* xo = (float*)Xout + xbase;
    *(float2*)&xo[d] = make_float2(o0x, o0y);
    *(float2*)&xo[128 + d] = make_float2(o1x, o1y);
  }
  if (Xout_bf) {
    unsigned short* xb = Xout_bf + xbase;
    *(ushort2*)&xb[d] = make_ushort2(f2bf(o0x), f2bf(o0y));
    *(ushort2*)&xb[128 + d] = make_ushort2(f2bf(o1x), f2bf(o1y));
  }

  // ---- fused d/t LayerNorm over the two 1024-halves (uniform branch) ----
  if (DNp) {
    float s4 = o0x + o0y + o1x + o1y;
    float q4 = o0x * o0x + o0y * o0y + o1x * o1x + o1y * o1y;
#pragma unroll
    for (int off = 32; off; off >>= 1) {
      s4 += __shfl_xor(s4, off, 64);
      q4 += __shfl_xor(q4, off, 64);
    }
    __shared__ float redS[8], redQ[8];
    if (lane == 0) { redS[h] = s4; redQ[h] = q4; }
    __syncthreads();
    const int b4 = (h >> 2) * 4;
    const float S = redS[b4] + redS[b4 + 1] + redS[b4 + 2] + redS[b4 + 3];
    const float Qs = redQ[b4] + redQ[b4 + 1] + redQ[b4 + 2] + redQ[b4 + 3];
    const float mean = S * (1.f / 1024.f);
    const float var = Qs * (1.f / 1024.f) - mean * mean;
    const float rstd = rsqrtf(var + 1e-6f);
    const float* gp = (h < 4) ? lnd_g : lnt_g;
    const float* bp = (h < 4) ? lnd_b : lnt_b;
    unsigned short* dst = ((h < 4) ? DNp : TNp) + row * 1024;
    const int hc = (h & 3) * 256 + d;
    float2 g0 = *(const float2*)&gp[hc];
    float2 b0 = *(const float2*)&bp[hc];
    *(ushort2*)&dst[hc] = make_ushort2(f2bf((o0x - mean) * rstd * g0.x + b0.x),
                                       f2bf((o0y - mean) * rstd * g0.y + b0.y));
    float2 g1 = *(const float2*)&gp[hc + 128];
    float2 b1 = *(const float2*)&bp[hc + 128];
    *(ushort2*)&dst[hc + 128] =
        make_ushort2(f2bf((o1x - mean) * rstd * g1.x + b1.x),
                     f2bf((o1y - mean) * rstd * g1.y + b1.y));
  }
}

__global__ __launch_bounds__(256) void final_matvec_kernel(
    const unsigned short* __restrict__ Hm, const float* __restrict__ wv,
    const float* __restrict__ b2, float* __restrict__ outp) {
  const long row = blockIdx.x;
  const int t = threadIdx.x;
  ushort4 hv = *(const ushort4*)&Hm[row * 1024 + t * 4];
  float4 wq = *(const float4*)&wv[t * 4];
  float s = bf2f(hv.x) * wq.x + bf2f(hv.y) * wq.y +
            bf2f(hv.z) * wq.z + bf2f(hv.w) * wq.w;
#pragma unroll
  for (int off = 32; off; off >>= 1) s += __shfl_xor(s, off, 64);
  __shared__ float red[4];
  if ((t & 63) == 0) red[t >> 6] = s;
  __syncthreads();
  if (t == 0) outp[row] = red[0] + red[1] + red[2] + red[3] + b2[0];
}

// ---------------------------------------------------------------------------
extern "C" void kernel_launch(void* const* d_in, const int* in_sizes, int n_in,
                              void* d_out, int out_size, void* d_ws,
                              size_t ws_size, hipStream_t stream) {
  const float* x_in = (const float*)d_in[0];
  const float* aln_g = (const float*)d_in[1];
  const float* aln_b = (const float*)d_in[2];
  const float* Wq_f = (const float*)d_in[3];
  const float* Wk_f = (const float*)d_in[4];
  const float* Wv_f = (const float*)d_in[5];
  const float* lnd_g = (const float*)d_in[6];
  const float* lnd_b = (const float*)d_in[7];
  const float* lnt_g = (const float*)d_in[8];
  const float* lnt_b = (const float*)d_in[9];
  const float* Wd1_f = (const float*)d_in[10];
  const float* bd1 = (const float*)d_in[11];
  const float* Wd2_f = (const float*)d_in[12];
  const float* bd2 = (const float*)d_in[13];
  const float* Wt1_f = (const float*)d_in[14];
  const float* bt1 = (const float*)d_in[15];
  const float* Wt2_f = (const float*)d_in[16];
  const float* bt2 = (const float*)d_in[17];
  const float* Wo1_f = (const float*)d_in[18];
  const float* bo1 = (const float*)d_in[19];
  const float* Wo2_f = (const float*)d_in[20];
  const float* bo2 = (const float*)d_in[21];

  const size_t R = 8192, D = 2048, HD = 1024;
  const size_t DD = D * D;
  const size_t WALL = (3 * 3 * DD + 4 * 2 * D * HD + HD * D) * 2;  // 108 MiB
  const size_t SLOT = 3 * DD * 2;                                  // 24 MiB
  const size_t ACT = R * D * 4 + R * D * 2 + R * 6144 * 2;         // 192 MiB

  auto cvt = [&](const float* src, unsigned short* dst, long n) {
    cvt_kernel<<<dim3((unsigned)(n / 1024)), dim3(256), 0, stream>>>(src, dst, n);
  };

  if (ws_size >= ACT + SLOT) {
    // ===================== fast path (8-phase GEMMs) =====================
    const bool planAll = ws_size >= ACT + WALL;
    hipFuncSetAttribute(reinterpret_cast<const void*>(gemm8_kernel),
                        hipFuncAttributeMaxDynamicSharedMemorySize, 131072);

    char* p = (char*)d_ws;
    float* Xf = (float*)p; p += R * D * 4;
    unsigned short* XN = (unsigned short*)p; p += R * D * 2;
    unsigned short* QKVb = (unsigned short*)p; p += R * 6144 * 2;
    unsigned short* Warea = (unsigned short*)p;

    unsigned short* H1d = QKVb;
    unsigned short* H1t = QKVb + R * 2048;
    unsigned short* Hfin = QKVb + R * 4096;
    unsigned short* DN = XN;
    unsigned short* TN = XN + R * HD;

    unsigned short* Wqkv_b = Warea;
    unsigned short* Wd1_b = Wqkv_b + 9 * DD;
    unsigned short* Wt1_b = Wd1_b + 2 * D * HD;
    unsigned short* Wd2_b = Wt1_b + 2 * D * HD;
    unsigned short* Wt2_b = Wd2_b + 2 * D * HD;
    unsigned short* Wo1_b = Wt2_b + 2 * D * HD;
    if (planAll) {
      for (int n = 0; n < 3; ++n) {
        cvt(Wq_f + n * DD, Wqkv_b + n * 3 * DD + 0 * DD, DD);
        cvt(Wk_f + n * DD, Wqkv_b + n * 3 * DD + 1 * DD, DD);
        cvt(Wv_f + n * DD, Wqkv_b + n * 3 * DD + 2 * DD, DD);
      }
      cvt(Wd1_f, Wd1_b, 2 * D * HD);
      cvt(Wt1_f, Wt1_b, 2 * D * HD);
      cvt(Wd2_f, Wd2_b, 2 * D * HD);
      cvt(Wt2_f, Wt2_b, 2 * D * HD);
      cvt(Wo1_f, Wo1_b, HD * D);
    }

    auto gemm8 = [&](const unsigned short* A, int lda, const unsigned short* B,
                     int N, int K, void* C, int ldc, const float* bias,
                     int relu, int of32, int resadd, const unsigned short* A2,
                     const unsigned short* B2, void* C2, const float* bias2) {
      const int dual = (A2 != nullptr);
      dim3 grid((dual ? 2 : 1) * (N / 256), 32);
      gemm8_kernel<<<grid, dim3(512), 131072, stream>>>(
          A, lda, B, K, C, ldc, bias, relu, of32, resadd, A2, B2, C2, bias2,
          dual);
    };

    for (int n = 0; n < 3; ++n) {
      ln_kernel<2048><<<8192, 256, 0, stream>>>(
          (n == 0) ? (const void*)x_in : (const void*)Xf, 0, 2048,
          aln_g + n * D, aln_b + n * D, XN, 2048);
      const unsigned short* Wqkv;
      if (planAll) {
        Wqkv = Wqkv_b + (size_t)n * 3 * DD;
      } else {
        cvt(Wq_f + n * DD, Warea + 0 * DD, DD);
        cvt(Wk_f + n * DD, Warea + 1 * DD, DD);
        cvt(Wv_f + n * DD, Warea + 2 * DD, DD);
        Wqkv = Warea;
      }
      gemm8(XN, 2048, Wqkv, 6144, 2048, QKVb, 6144, nullptr, 0, 0, 0,
            nullptr, nullptr, nullptr, nullptr);
      attn_glue_kernel<<<8192, 512, 0, stream>>>(
          QKVb, QKVb + 2048, QKVb + 4096, 6144,
          (n == 0) ? (const void*)x_in : (const void*)Xf, 0, Xf, 0,
          (n == 2) ? XN : nullptr,
          (n < 2) ? DN : nullptr, (n < 2) ? TN : nullptr,
          (n < 2) ? lnd_g + n * HD : nullptr, (n < 2) ? lnd_b + n * HD : nullptr,
          (n < 2) ? lnt_g + n * HD : nullptr, (n < 2) ? lnt_b + n * HD : nullptr);

      if (n < 2) {
        const size_t fo = (size_t)n * D * HD;
        const unsigned short *w1d, *w1t, *w2d, *w2t;
        if (planAll) {
          w1d = Wd1_b + fo; w1t = Wt1_b + fo; w2d = Wd2_b + fo; w2t = Wt2_b + fo;
        } else {
          cvt(Wd1_f + fo, Warea + 0 * D * HD, D * HD);
          cvt(Wt1_f + fo, Warea + 1 * D * HD, D * HD);
          cvt(Wd2_f + fo, Warea + 2 * D * HD, D * HD);
          cvt(Wt2_f + fo, Warea + 3 * D * HD, D * HD);
          w1d = Warea; w1t = Warea + D * HD; w2d = Warea + 2 * D * HD;
          w2t = Warea + 3 * D * HD;
        }
        gemm8(DN, 1024, w1d, 2048, 1024, H1d, 2048, bd1 + n * D, 1, 0, 0,
              TN, w1t, H1t, bt1 + n * D);
        gemm8(H1d, 2048, w2d, 1024, 2048, Xf, 2048, bd2 + n * HD, 0, 1, 1,
              H1t, w2t, Xf + HD, bt2 + n * HD);
      }
    }

    // final head
    const unsigned short* Wo1p;
    if (planAll) {
      Wo1p = Wo1_b;
    } else {
      cvt(Wo1_f, Warea, HD * D);
      Wo1p = Warea;
    }
    gemm8(XN, 2048, Wo1p, 1024, 2048, Hfin, 1024, bo1, 1, 0, 0,
          nullptr, nullptr, nullptr, nullptr);
    final_matvec_kernel<<<8192, 256, 0, stream>>>(Hfin, Wo2_f, bo2,
                                                  (float*)d_out);
    return;
  }

  // ======================= legacy fallback path =======================
  const size_t PLB = R * D * 2;
  const size_t XFZ = R * D * 4;
  const size_t SLOT1 = DD * 2;
  const bool planAll = ws_size >= XFZ + 4 * PLB + WALL;
  const bool xIsF32 = planAll || ws_size >= XFZ + 4 * PLB + SLOT1;

  char* p = (char*)d_ws;
  float* Xf = nullptr;
  unsigned short* Xb = nullptr;
  if (xIsF32) { Xf = (float*)p; p += XFZ; } else { Xb = (unsigned short*)p; p += PLB; }
  unsigned short* XN = (unsigned short*)p; p += PLB;
  unsigned short* Qb = (unsigned short*)p; p += PLB;
  unsigned short* Kb = (unsigned short*)p; p += PLB;
  unsigned short* Vb = (unsigned short*)p; p += PLB;
  unsigned short* Warea = (unsigned short*)p;

  void* X = xIsF32 ? (void*)Xf : (void*)Xb;
  const int xres_mode = xIsF32 ? 1 : 2;
  unsigned short* H1 = Qb;
  unsigned short* DN = XN;
  unsigned short* TN = XN + R * HD;
  unsigned short* Hfin = Vb;

  unsigned short* Wq_b = Warea;
  unsigned short* Wk_b = Wq_b + 3 * DD;
  unsigned short* Wv_b = Wk_b + 3 * DD;
  unsigned short* Wd1_b = Wv_b + 3 * DD;
  unsigned short* Wd2_b = Wd1_b + 2 * D * HD;
  unsigned short* Wt1_b = Wd2_b + 2 * D * HD;
  unsigned short* Wt2_b = Wt1_b + 2 * D * HD;
  unsigned short* Wo1_b = Wt2_b + 2 * D * HD;
  if (planAll) {
    cvt(Wq_f, Wq_b, 3 * DD);
    cvt(Wk_f, Wk_b, 3 * DD);
    cvt(Wv_f, Wv_b, 3 * DD);
    cvt(Wd1_f, Wd1_b, 2 * D * HD);
    cvt(Wd2_f, Wd2_b, 2 * D * HD);
    cvt(Wt1_f, Wt1_b, 2 * D * HD);
    cvt(Wt2_f, Wt2_b, 2 * D * HD);
    cvt(Wo1_f, Wo1_b, HD * D);
  }
  auto wbf = [&](const float* src_base, unsigned short* pre_base, size_t off,
                 size_t cnt) -> const unsigned short* {
    if (planAll) return pre_base + off;
    cvt(src_base + off, Warea, (long)cnt);
    return Warea;
  };
  auto gemm = [&](const unsigned short* A, int lda, const unsigned short* B,
                  int N, int K, void* C, int ldc, const float* bias,
                  const void* res, int res_mode, int ldres, int relu, int of32) {
    dim3 grid(N / 128, 8192 / 128);
    gemm_bt_kernel<<<grid, dim3(256), 0, stream>>>(
        A, lda, B, K, C, ldc, bias, res, res_mode, ldres, relu, of32);
  };

  for (int n = 0; n < 3; ++n) {
    const void* lin = (n == 0) ? (const void*)x_in : (const void*)X;
    const int lin_bf16 = (n == 0) ? 0 : (xIsF32 ? 0 : 1);
    ln_kernel<2048><<<8192, 256, 0, stream>>>(lin, lin_bf16, 2048,
                                              aln_g + n * D, aln_b + n * D, XN, 2048);
    const size_t wo = (size_t)n * DD;
    gemm(XN, 2048, wbf(Wq_f, Wq_b, wo, DD), 2048, 2048, Qb, 2048,
         nullptr, nullptr, 0, 0, 0, 0);
    gemm(XN, 2048, wbf(Wk_f, Wk_b, wo, DD), 2048, 2048, Kb, 2048,
         nullptr, nullptr, 0, 0, 0, 0);
    gemm(XN, 2048, wbf(Wv_f, Wv_b, wo, DD), 2048, 2048, Vb, 2048,
         nullptr, nullptr, 0, 0, 0, 0);
    attn_glue_kernel<<<8192, 512, 0, stream>>>(
        Qb, Kb, Vb, 2048, (n == 0) ? (const void*)x_in : (const void*)X,
        (n == 0) ? 0 : (xIsF32 ? 0 : 1), X, xIsF32 ? 0 : 1,
        (n == 2 && xIsF32) ? XN : nullptr,
        nullptr, nullptr, nullptr, nullptr, nullptr, nullptr);

    if (n < 2) {
      const size_t fo = (size_t)n * D * HD;
      ln_kernel<1024><<<8192, 256, 0, stream>>>(X, !xIsF32, 2048,
                                                lnd_g + n * HD, lnd_b + n * HD, DN, 1024);
      const void* Xt = xIsF32 ? (const void*)(Xf + HD) : (const void*)(Xb + HD);
      ln_kernel<1024><<<8192, 256, 0, stream>>>(Xt, !xIsF32, 2048,
                                                lnt_g + n * HD, lnt_b + n * HD, TN, 1024);
      void* Xd2 = X;
      void* Xt2 = xIsF32 ? (void*)(Xf + HD) : (void*)(Xb + HD);
      gemm(DN, 1024, wbf(Wd1_f, Wd1_b, fo, D * HD), 2048, 1024, H1, 2048,
           bd1 + n * D, nullptr, 0, 0, 1, 0);
      gemm(H1, 2048, wbf(Wd2_f, Wd2_b, fo, D * HD), 1024, 2048, Xd2, 2048,
           bd2 + n * HD, Xd2, xres_mode, 2048, 0, xIsF32 ? 1 : 0);
      gemm(TN, 1024, wbf(Wt1_f, Wt1_b, fo, D * HD), 2048, 1024, H1, 2048,
           bt1 + n * D, nullptr, 0, 0, 1, 0);
      gemm(H1, 2048, wbf(Wt2_f, Wt2_b, fo, D * HD), 1024, 2048, Xt2, 2048,
           bt2 + n * HD, Xt2, xres_mode, 2048, 0, xIsF32 ? 1 : 0);
    }
  }

  const unsigned short* Afin = xIsF32 ? XN : Xb;
  gemm(Afin, 2048, wbf(Wo1_f, Wo1_b, 0, HD * D), 1024, 2048, Hfin, 1024,
       bo1, nullptr, 0, 0, 1, 0);
  final_matvec_kernel<<<8192, 256, 0, stream>>>(Hfin, Wo2_f, bo2, (float*)d_out);
}

// Round 9
// 1340.782 us; speedup vs baseline: 2.1767x; 2.1767x over previous
//
#include <hip/hip_runtime.h>
#include <stdint.h>

// ---------------------------------------------------------------------------
// PairwiseAttentionLinear — fp32 in/out on device.
// Round 9: gemm8 K-loop = counted-lgkm overlap with kk-SPLIT sub-phases.
// Read groups r0..r5 (6/6/2/2/4/4 ds_reads); each MFMA octet runs with the
// next group in flight (LGKM counts the in-flight group). Max live fragments
// 16 (64 VGPR) vs r8's 96 -> no spill. 3 barriers/tile, hazard invariants
// identical to rounds 5-7.
// ---------------------------------------------------------------------------

typedef __bf16 bf16x8 __attribute__((ext_vector_type(8)));
typedef float f32x4 __attribute__((ext_vector_type(4)));

static __device__ __forceinline__ float bf2f(unsigned short u) {
  unsigned int x = ((unsigned int)u) << 16;
  float f;
  __builtin_memcpy(&f, &x, 4);
  return f;
}
static __device__ __forceinline__ unsigned short f2bf(float f) {
  unsigned int x;
  __builtin_memcpy(&x, &f, 4);
  x += 0x7fffu + ((x >> 16) & 1u);  // RNE
  return (unsigned short)(x >> 16);
}

static __device__ __forceinline__ void gload_lds16(const void* g, void* l) {
  __builtin_amdgcn_global_load_lds(
      (const __attribute__((address_space(1))) unsigned int*)g,
      (__attribute__((address_space(3))) unsigned int*)l, 16, 0, 0);
}

__global__ __launch_bounds__(256) void cvt_kernel(
    const float* __restrict__ in, unsigned short* __restrict__ out, long n) {
  const long i = ((long)blockIdx.x * 256 + threadIdx.x) * 4;
  if (i + 3 < n) {
    float4 f = *(const float4*)(in + i);
    *(ushort4*)(out + i) = make_ushort4(f2bf(f.x), f2bf(f.y), f2bf(f.z), f2bf(f.w));
  }
}

// ---------------------------------------------------------------------------
#define BARRIER __builtin_amdgcn_s_barrier()
#define LGKM(N)                                                     \
  do {                                                              \
    asm volatile("s_waitcnt lgkmcnt(" #N ")" ::: "memory");         \
    __builtin_amdgcn_sched_barrier(0);                              \
  } while (0)
#define VMC(N)                                                      \
  do {                                                              \
    asm volatile("s_waitcnt vmcnt(" #N ")" ::: "memory");           \
    __builtin_amdgcn_sched_barrier(0);                              \
  } while (0)

__global__ __launch_bounds__(512, 2) void gemm8_kernel(
    const unsigned short* __restrict__ A, int lda,
    const unsigned short* __restrict__ B, int K,
    void* __restrict__ Cp, int ldc, const float* __restrict__ bias,
    int relu, int out_f32, int resadd,
    const unsigned short* __restrict__ A2, const unsigned short* __restrict__ B2,
    void* __restrict__ C2p, const float* __restrict__ bias2, int dual) {
  extern __shared__ __align__(16) char smem[];  // 131072 B

  const int tid = threadIdx.x;
  const int lane = tid & 63;
  const int w = tid >> 6;
  const int wm = w >> 2;  // 0..1
  const int wn = w & 3;   // 0..3
  const long brow = (long)blockIdx.y * 256;

  const unsigned short* Ap = A;
  const unsigned short* Bp = B;
  const float* bi = bias;
  void* Cq = Cp;
  long bcol;
  if (dual && (int)blockIdx.x >= (int)(gridDim.x >> 1)) {
    Ap = A2; Bp = B2; bi = bias2; Cq = C2p;
    bcol = (long)(blockIdx.x - (gridDim.x >> 1)) * 256;
  } else {
    bcol = (long)blockIdx.x * 256;
  }

  const int NT = K >> 6;  // K-tiles of 64

  // ---- staging addressing, hoisted
  const int lrA = tid >> 3;
  const int scb = ((tid & 7) * 16) ^ (((tid >> 3) & 7) << 4);  // pre-swz src
  const unsigned wb = (unsigned)(tid & ~63) * 16;
  const long ldab = (long)lda * 2;
  const long ldbb = (long)K * 2;
  const char* gA = (const char*)Ap + (brow + lrA) * ldab + scb;
  const char* gB = (const char*)Bp + (bcol + lrA) * ldbb + scb;
  const long a64 = 64 * ldab, a128 = 128 * ldab, a192 = 192 * ldab;
  const long b64 = 64 * ldbb, b128 = 128 * ldbb, b192 = 192 * ldbb;

#define STAGE_A(bb, off)                                        \
  do {                                                          \
    gload_lds16(gA + (off), smem + (bb) + wb);                  \
    gload_lds16(gA + a64 + (off), smem + (bb) + 8192 + wb);     \
    gload_lds16(gA + a128 + (off), smem + (bb) + 16384 + wb);   \
    gload_lds16(gA + a192 + (off), smem + (bb) + 24576 + wb);   \
  } while (0)
#define STAGE_B(bb, off)                                        \
  do {                                                          \
    gload_lds16(gB + (off), smem + (bb) + 32768 + wb);          \
    gload_lds16(gB + b64 + (off), smem + (bb) + 40960 + wb);    \
    gload_lds16(gB + b128 + (off), smem + (bb) + 49152 + wb);   \
    gload_lds16(gB + b192 + (off), smem + (bb) + 57344 + wb);   \
  } while (0)

  f32x4 acc[8][4];
  const f32x4 fz = {0.f, 0.f, 0.f, 0.f};
#pragma unroll
  for (int m = 0; m < 8; ++m)
#pragma unroll
    for (int n = 0; n < 4; ++n) acc[m][n] = fz;

  const int frow = lane & 15;
  const int fkb = (lane >> 4) * 16;  // k-byte within 64-col row
  const int fswz = (lane & 7) << 4;  // T2 read-side swizzle

#define RDA(dst, CB, M, KK)                                                   \
  dst = *(const bf16x8*)(smem + (CB) + (wm * 128 + (M) * 16 + frow) * 128 +   \
                         (((KK) * 64 + fkb) ^ fswz))
#define RDB(dst, CB, N, KK)                                                   \
  dst = *(const bf16x8*)(smem + (CB) + 32768 +                                \
                         (wn * 64 + (N) * 16 + frow) * 128 +                  \
                         (((KK) * 64 + fkb) ^ fswz))

  // 8 MFMAs: 4 m-values x 2 n-values, single kk (arrays select kk)
#define MM_Q(A4, B2, MO, NO)                                                  \
  do {                                                                        \
    _Pragma("unroll") for (int mm = 0; mm < 4; ++mm)                          \
    _Pragma("unroll") for (int nn = 0; nn < 2; ++nn)                          \
        acc[(MO) + mm][(NO) + nn] = __builtin_amdgcn_mfma_f32_16x16x32_bf16(  \
            A4[mm], B2[nn], acc[(MO) + mm][(NO) + nn], 0, 0, 0);              \
  } while (0)

  bf16x8 aL0[4], aL1[4], aH0[4], aH1[4];
  bf16x8 bL0[2], bL1[2], bH0[2], bH1[2];

  // ---- prologue: stage tiles 0 (buf0) and 1 (buf1); wait tile 0
  STAGE_A(0, 0);
  STAGE_B(0, 0);
  STAGE_A(65536, 128);
  STAGE_B(65536, 128);
  VMC(8);
  BARRIER;
  long soff = 256;  // staging byte-offset of tile t+2

  // Counted-lgkm sub-phase schedule. DS reads complete IN ORDER per wave.
  // Groups: r0{bL0,aL0}=6, r1{bL1,aL1}=6, r2{bH0}=2, r3{bH1}=2, r4{aH0}=4,
  // r5{aH1}=4. Each MFMA octet runs with the next group in flight.
#define TILE_IT(T, CB)                                                        \
  do {                                                                        \
    /* r0 + r1 */                                                             \
    RDB(bL0[0], CB, 0, 0); RDB(bL0[1], CB, 1, 0);                             \
    RDA(aL0[0], CB, 0, 0); RDA(aL0[1], CB, 1, 0);                             \
    RDA(aL0[2], CB, 2, 0); RDA(aL0[3], CB, 3, 0);                             \
    RDB(bL1[0], CB, 0, 1); RDB(bL1[1], CB, 1, 1);                             \
    RDA(aL1[0], CB, 0, 1); RDA(aL1[1], CB, 1, 1);                             \
    RDA(aL1[2], CB, 2, 1); RDA(aL1[3], CB, 3, 1);                             \
    LGKM(6); /* r0 done, r1 in flight */                                      \
    __builtin_amdgcn_s_setprio(1);                                            \
    MM_Q(aL0, bL0, 0, 0);                                                     \
    __builtin_amdgcn_s_setprio(0);                                            \
    RDB(bH0[0], CB, 2, 0); RDB(bH0[1], CB, 3, 0); /* r2 */                    \
    LGKM(2); /* r1 done, r2 in flight */                                      \
    __builtin_amdgcn_s_setprio(1);                                            \
    MM_Q(aL1, bL1, 0, 0);                                                     \
    __builtin_amdgcn_s_setprio(0);                                            \
    RDB(bH1[0], CB, 2, 1); RDB(bH1[1], CB, 3, 1); /* r3 */                    \
    LGKM(2); /* r2 done, r3 in flight */                                      \
    __builtin_amdgcn_s_setprio(1);                                            \
    MM_Q(aL0, bH0, 0, 2);                                                     \
    __builtin_amdgcn_s_setprio(0);                                            \
    RDA(aH0[0], CB, 4, 0); RDA(aH0[1], CB, 5, 0); /* r4 */                    \
    RDA(aH0[2], CB, 6, 0); RDA(aH0[3], CB, 7, 0);                             \
    LGKM(4); /* r3 done, r4 in flight */                                      \
    __builtin_amdgcn_s_setprio(1);                                            \
    MM_Q(aL1, bH1, 0, 2);                                                     \
    __builtin_amdgcn_s_setprio(0);                                            \
    RDA(aH1[0], CB, 4, 1); RDA(aH1[1], CB, 5, 1); /* r5 */                    \
    RDA(aH1[2], CB, 6, 1); RDA(aH1[3], CB, 7, 1);                             \
    LGKM(4); /* r4 done, r5 in flight; all B-reads (r0-r3) done */            \
    BARRIER; /* all waves past B-reads -> B staging safe */                   \
    if ((T) + 2 < NT) STAGE_B(CB, soff);                                      \
    __builtin_amdgcn_s_setprio(1);                                            \
    MM_Q(aH0, bL0, 4, 0); /* r5 drains under this */                          \
    __builtin_amdgcn_s_setprio(0);                                            \
    LGKM(0); /* all A-reads done */                                           \
    BARRIER; /* all waves -> A staging safe */                                \
    if ((T) + 2 < NT) {                                                       \
      STAGE_A(CB, soff);                                                      \
      VMC(8); /* tile T+1 fully landed */                                     \
    } else {                                                                  \
      VMC(0); /* tail drain */                                                \
    }                                                                         \
    __builtin_amdgcn_s_setprio(1);                                            \
    MM_Q(aH1, bL1, 4, 0);                                                     \
    MM_Q(aH0, bH0, 4, 2);                                                     \
    MM_Q(aH1, bH1, 4, 2);                                                     \
    __builtin_amdgcn_s_setprio(0);                                            \
    BARRIER; /* tile boundary: all waves passed VMC */                        \
    soff += 128;                                                              \
  } while (0)

  for (int t = 0; t < NT; t += 2) {
    TILE_IT(t, 0);
    TILE_IT(t + 1, 65536);
  }

  // ---- epilogue: C/D layout col=lane&15, row=(lane>>4)*4+reg [m89]
  const long rb0 = brow + wm * 128 + (lane >> 4) * 4;
  const long cb0 = bcol + wn * 64 + (lane & 15);
#pragma unroll
  for (int m = 0; m < 8; ++m) {
#pragma unroll
    for (int n = 0; n < 4; ++n) {
      const long col = cb0 + n * 16;
      const float bv = bi ? bi[col] : 0.f;
#pragma unroll
      for (int j = 0; j < 4; ++j) {
        const long r = rb0 + m * 16 + j;
        float v = acc[m][n][j] + bv;
        if (relu) v = fmaxf(v, 0.f);
        if (out_f32) {
          float* cp = (float*)Cq + r * (long)ldc + col;
          if (resadd) v += *cp;
          *cp = v;
        } else {
          ((unsigned short*)Cq)[r * (long)ldc + col] = f2bf(v);
        }
      }
    }
  }
#undef TILE_IT
#undef STAGE_A
#undef STAGE_B
#undef RDA
#undef RDB
#undef MM_Q
}

// ---------------------------------------------------------------------------
// Legacy 128x128 GEMM — fallback path only.
// ---------------------------------------------------------------------------
__global__ __launch_bounds__(256) void gemm_bt_kernel(
    const unsigned short* __restrict__ A, int lda,
    const unsigned short* __restrict__ B, int K,
    void* __restrict__ Cp, int ldc,
    const float* __restrict__ bias,
    const void* __restrict__ res, int res_mode, int ldres,
    int relu, int out_f32) {
  __shared__ __align__(16) unsigned short As[128 * 32];
  __shared__ __align__(16) unsigned short Bs[128 * 32];

  const int t = threadIdx.x;
  const int lane = t & 63;
  const int w = t >> 6;
  const int wr = (w >> 1) * 64;
  const int wc = (w & 1) * 64;
  const long brow = (long)blockIdx.y * 128;
  const long bcol = (long)blockIdx.x * 128;

  const int srow = lane >> 2;
  const int scol = (lane & 3) * 8;
  const unsigned short* Ab = A + (brow + w * 32 + srow) * (long)lda + scol;
  const unsigned short* Bb = B + (bcol + w * 32 + srow) * (long)K + scol;
  unsigned short* Asb = &As[(w * 32) * 32];
  unsigned short* Bsb = &Bs[(w * 32) * 32];

  f32x4 acc[4][4];
  const f32x4 fzero = {0.f, 0.f, 0.f, 0.f};
#pragma unroll
  for (int m = 0; m < 4; ++m)
#pragma unroll
    for (int n = 0; n < 4; ++n) acc[m][n] = fzero;

  const int fr = lane & 15;
  const int fk = (lane >> 4) * 8;

  for (int kt = 0; kt < K; kt += 32) {
    gload_lds16(Ab + kt, Asb);
    gload_lds16(Ab + 16 * (long)lda + kt, Asb + 16 * 32);
    gload_lds16(Bb + kt, Bsb);
    gload_lds16(Bb + 16 * (long)K + kt, Bsb + 16 * 32);
    __syncthreads();

    bf16x8 af[4], bfv[4];
#pragma unroll
    for (int m = 0; m < 4; ++m)
      af[m] = *(const bf16x8*)&As[(wr + m * 16 + fr) * 32 + fk];
#pragma unroll
    for (int n = 0; n < 4; ++n)
      bfv[n] = *(const bf16x8*)&Bs[(wc + n * 16 + fr) * 32 + fk];
#pragma unroll
    for (int m = 0; m < 4; ++m)
#pragma unroll
      for (int n = 0; n < 4; ++n)
        acc[m][n] = __builtin_amdgcn_mfma_f32_16x16x32_bf16(af[m], bfv[n],
                                                            acc[m][n], 0, 0, 0);
    __syncthreads();
  }

  const long rbase = brow + wr + (lane >> 4) * 4;
#pragma unroll
  for (int m = 0; m < 4; ++m) {
#pragma unroll
    for (int n = 0; n < 4; ++n) {
      const long col = bcol + wc + n * 16 + fr;
      const float bv = bias ? bias[col] : 0.f;
#pragma unroll
      for (int j = 0; j < 4; ++j) {
        const long r = rbase + m * 16 + j;
        float v = acc[m][n][j] + bv;
        if (relu) v = fmaxf(v, 0.f);
        if (res_mode == 1)
          v += ((const float*)res)[r * (long)ldres + col];
        else if (res_mode == 2)
          v += bf2f(((const unsigned short*)res)[r * (long)ldres + col]);
        if (out_f32)
          ((float*)Cp)[r * (long)ldc + col] = v;
        else
          ((unsigned short*)Cp)[r * (long)ldc + col] = f2bf(v);
      }
    }
  }
}

// ---------------------------------------------------------------------------
template <int L>
__global__ __launch_bounds__(256) void ln_kernel(
    const void* __restrict__ inp, int in_bf16, int ldin,
    const float* __restrict__ g, const float* __restrict__ b,
    unsigned short* __restrict__ outp, int ldout) {
  constexpr int VEC = L / 256;
  const long row = blockIdx.x;
  const int t = threadIdx.x;
  float v[VEC];
  if (in_bf16) {
    const unsigned short* p = (const unsigned short*)inp + row * (long)ldin + t * VEC;
#pragma unroll
    for (int i = 0; i < VEC; i += 4) {
      ushort4 u = *(const ushort4*)(p + i);
      v[i] = bf2f(u.x); v[i + 1] = bf2f(u.y); v[i + 2] = bf2f(u.z); v[i + 3] = bf2f(u.w);
    }
  } else {
    const float* p = (const float*)inp + row * (long)ldin + t * VEC;
#pragma unroll
    for (int i = 0; i < VEC; i += 4) {
      float4 f = *(const float4*)(p + i);
      v[i] = f.x; v[i + 1] = f.y; v[i + 2] = f.z; v[i + 3] = f.w;
    }
  }
  float s = 0.f, sq = 0.f;
#pragma unroll
  for (int i = 0; i < VEC; ++i) { s += v[i]; sq += v[i] * v[i]; }
#pragma unroll
  for (int off = 32; off; off >>= 1) {
    s += __shfl_xor(s, off, 64);
    sq += __shfl_xor(sq, off, 64);
  }
  __shared__ float red[8];
  if ((t & 63) == 0) { red[t >> 6] = s; red[4 + (t >> 6)] = sq; }
  __syncthreads();
  s = red[0] + red[1] + red[2] + red[3];
  sq = red[4] + red[5] + red[6] + red[7];
  const float mean = s * (1.f / L);
  const float var = sq * (1.f / L) - mean * mean;
  const float rstd = rsqrtf(var + 1e-6f);
  unsigned short* op = outp + row * (long)ldout + t * VEC;
  const float* gp = g + t * VEC;
  const float* bp = b + t * VEC;
#pragma unroll
  for (int i = 0; i < VEC; i += 4) {
    float4 gg = *(const float4*)(gp + i);
    float4 bb = *(const float4*)(bp + i);
    *(ushort4*)(op + i) = make_ushort4(
        f2bf((v[i + 0] - mean) * rstd * gg.x + bb.x),
        f2bf((v[i + 1] - mean) * rstd * gg.y + bb.y),
        f2bf((v[i + 2] - mean) * rstd * gg.z + bb.z),
        f2bf((v[i + 3] - mean) * rstd * gg.w + bb.w));
  }
}

// ---------------------------------------------------------------------------
// Pairwise attention glue + optional fused d/t LayerNorms.
// ---------------------------------------------------------------------------
__global__ __launch_bounds__(512) void attn_glue_kernel(
    const unsigned short* __restrict__ Q, const unsigned short* __restrict__ Kq,
    const unsigned short* __restrict__ V, int ld, const void* __restrict__ Xres,
    int res_bf16, void* __restrict__ Xout, int out_bf16,
    unsigned short* __restrict__ Xout_bf,
    unsigned short* __restrict__ DNp, unsigned short* __restrict__ TNp,
    const float* __restrict__ lnd_g, const float* __restrict__ lnd_b,
    const float* __restrict__ lnt_g, const float* __restrict__ lnt_b) {
  const long row = blockIdx.x;
  const int h = threadIdx.x >> 6;
  const int lane = threadIdx.x & 63;
  const long qbase = row * (long)ld + h * 256;
  const long xbase = row * 2048 + h * 256;
  const int d = lane * 2;

  ushort2 q0 = *(const ushort2*)&Q[qbase + d];
  ushort2 q1 = *(const ushort2*)&Q[qbase + 128 + d];
  ushort2 k0 = *(const ushort2*)&Kq[qbase + d];
  ushort2 k1 = *(const ushort2*)&Kq[qbase + 128 + d];
  ushort2 v0 = *(const ushort2*)&V[qbase + d];
  ushort2 v1 = *(const ushort2*)&V[qbase + 128 + d];

  const float q0x = bf2f(q0.x), q0y = bf2f(q0.y);
  const float q1x = bf2f(q1.x), q1y = bf2f(q1.y);
  const float k0x = bf2f(k0.x), k0y = bf2f(k0.y);
  const float k1x = bf2f(k1.x), k1y = bf2f(k1.y);

  float s00 = q0x * k0x + q0y * k0y;
  float s01 = q0x * k1x + q0y * k1y;
  float s10 = q1x * k0x + q1y * k0y;
  float s11 = q1x * k1x + q1y * k1y;
#pragma unroll
  for (int off = 32; off; off >>= 1) {
    s00 += __shfl_xor(s00, off, 64);
    s01 += __shfl_xor(s01, off, 64);
    s10 += __shfl_xor(s10, off, 64);
    s11 += __shfl_xor(s11, off, 64);
  }
  const float SC = 0.088388347648318447f;  // 1/sqrt(128)
  s00 *= SC; s01 *= SC; s10 *= SC; s11 *= SC;
  const float m0 = fmaxf(s00, s01), m1 = fmaxf(s10, s11);
  const float e00 = __expf(s00 - m0), e01 = __expf(s01 - m0);
  const float e10 = __expf(s10 - m1), e11 = __expf(s11 - m1);
  const float i0 = 1.f / (e00 + e01), i1 = 1.f / (e10 + e11);
  const float a00 = e00 * i0, a01 = e01 * i0;
  const float a10 = e10 * i1, a11 = e11 * i1;

  const float v0x = bf2f(v0.x), v0y = bf2f(v0.y);
  const float v1x = bf2f(v1.x), v1y = bf2f(v1.y);
  float o0x = a00 * v0x + a01 * v1x, o0y = a00 * v0y + a01 * v1y;
  float o1x = a10 * v0x + a11 * v1x, o1y = a10 * v0y + a11 * v1y;

  if (res_bf16) {
    const unsigned short* xr = (const unsigned short*)Xres + xbase;
    ushort2 ra = *(const ushort2*)&xr[d];
    ushort2 rb = *(const ushort2*)&xr[128 + d];
    o0x += bf2f(ra.x); o0y += bf2f(ra.y); o1x += bf2f(rb.x); o1y += bf2f(rb.y);
  } else {
    const float* xr = (const float*)Xres + xbase;
    float2 ra = *(const float2*)&xr[d];
    float2 rb = *(const float2*)&xr[128 + d];
    o0x += ra.x; o0y += ra.y; o1x += rb.x; o1y += rb.y;
  }
  if (out_bf16) {
    unsigned short* xo = (unsigned short*)Xout + xbase;
    *(ushort2*)&xo[d] = make_ushort2(f2bf(o0x), f2bf(o0y));
    *(ushort2*)&xo[128 + d] = make_ushort2(f2bf(o1x), f2bf(o1y));
  } else {
    float* xo = (float*)Xout + xbase;
    *(float2*)&xo[d] = make_float2(o0x, o0y);
    *(float2*)&xo[128 + d] = make_float2(o1x, o1y);
  }
  if (Xout_bf) {
    unsigned short* xb = Xout_bf + xbase;
    *(ushort2*)&xb[d] = make_ushort2(f2bf(o0x), f2bf(o0y));
    *(ushort2*)&xb[128 + d] = make_ushort2(f2bf(o1x), f2bf(o1y));
  }

  // ---- fused d/t LayerNorm over the two 1024-halves (uniform branch) ----
  if (DNp) {
    float s4 = o0x + o0y + o1x + o1y;
    float q4 = o0x * o0x + o0y * o0y + o1x * o1x + o1y * o1y;
#pragma unroll
    for (int off = 32; off; off >>= 1) {
      s4 += __shfl_xor(s4, off, 64);
      q4 += __shfl_xor(q4, off, 64);
    }
    __shared__ float redS[8], redQ[8];
    if (lane == 0) { redS[h] = s4; redQ[h] = q4; }
    __syncthreads();
    const int b4 = (h >> 2) * 4;
    const float S = redS[b4] + redS[b4 + 1] + redS[b4 + 2] + redS[b4 + 3];
    const float Qs = redQ[b4] + redQ[b4 + 1] + redQ[b4 + 2] + redQ[b4 + 3];
    const float mean = S * (1.f / 1024.f);
    const float var = Qs * (1.f / 1024.f) - mean * mean;
    const float rstd = rsqrtf(var + 1e-6f);
    const float* gp = (h < 4) ? lnd_g : lnt_g;
    const float* bp = (h < 4) ? lnd_b : lnt_b;
    unsigned short* dst = ((h < 4) ? DNp : TNp) + row * 1024;
    const int hc = (h & 3) * 256 + d;
    float2 g0 = *(const float2*)&gp[hc];
    float2 b0 = *(const float2*)&bp[hc];
    *(ushort2*)&dst[hc] = make_ushort2(f2bf((o0x - mean) * rstd * g0.x + b0.x),
                                       f2bf((o0y - mean) * rstd * g0.y + b0.y));
    float2 g1 = *(const float2*)&gp[hc + 128];
    float2 b1 = *(const float2*)&bp[hc + 128];
    *(ushort2*)&dst[hc + 128] =
        make_ushort2(f2bf((o1x - mean) * rstd * g1.x + b1.x),
                     f2bf((o1y - mean) * rstd * g1.y + b1.y));
  }
}

__global__ __launch_bounds__(256) void final_matvec_kernel(
    const unsigned short* __restrict__ Hm, const float* __restrict__ wv,
    const float* __restrict__ b2, float* __restrict__ outp) {
  const long row = blockIdx.x;
  const int t = threadIdx.x;
  ushort4 hv = *(const ushort4*)&Hm[row * 1024 + t * 4];
  float4 wq = *(const float4*)&wv[t * 4];
  float s = bf2f(hv.x) * wq.x + bf2f(hv.y) * wq.y +
            bf2f(hv.z) * wq.z + bf2f(hv.w) * wq.w;
#pragma unroll
  for (int off = 32; off; off >>= 1) s += __shfl_xor(s, off, 64);
  __shared__ float red[4];
  if ((t & 63) == 0) red[t >> 6] = s;
  __syncthreads();
  if (t == 0) outp[row] = red[0] + red[1] + red[2] + red[3] + b2[0];
}

// ---------------------------------------------------------------------------
extern "C" void kernel_launch(void* const* d_in, const int* in_sizes, int n_in,
                              void* d_out, int out_size, void* d_ws,
                              size_t ws_size, hipStream_t stream) {
  const float* x_in = (const float*)d_in[0];
  const float* aln_g = (const float*)d_in[1];
  const float* aln_b = (const float*)d_in[2];
  const float* Wq_f = (const float*)d_in[3];
  const float* Wk_f = (const float*)d_in[4];
  const float* Wv_f = (const float*)d_in[5];
  const float* lnd_g = (const float*)d_in[6];
  const float* lnd_b = (const float*)d_in[7];
  const float* lnt_g = (const float*)d_in[8];
  const float* lnt_b = (const float*)d_in[9];
  const float* Wd1_f = (const float*)d_in[10];
  const float* bd1 = (const float*)d_in[11];
  const float* Wd2_f = (const float*)d_in[12];
  const float* bd2 = (const float*)d_in[13];
  const float* Wt1_f = (const float*)d_in[14];
  const float* bt1 = (const float*)d_in[15];
  const float* Wt2_f = (const float*)d_in[16];
  const float* bt2 = (const float*)d_in[17];
  const float* Wo1_f = (const float*)d_in[18];
  const float* bo1 = (const float*)d_in[19];
  const float* Wo2_f = (const float*)d_in[20];
  const float* bo2 = (const float*)d_in[21];

  const size_t R = 8192, D = 2048, HD = 1024;
  const size_t DD = D * D;
  const size_t WALL = (3 * 3 * DD + 4 * 2 * D * HD + HD * D) * 2;  // 108 MiB
  const size_t SLOT = 3 * DD * 2;                                  // 24 MiB
  const size_t ACT = R * D * 4 + R * D * 2 + R * 6144 * 2;         // 192 MiB

  auto cvt = [&](const float* src, unsigned short* dst, long n) {
    cvt_kernel<<<dim3((unsigned)(n / 1024)), dim3(256), 0, stream>>>(src, dst, n);
  };

  if (ws_size >= ACT + SLOT) {
    // ===================== fast path (8-phase GEMMs) =====================
    const bool planAll = ws_size >= ACT + WALL;
    hipFuncSetAttribute(reinterpret_cast<const void*>(gemm8_kernel),
                        hipFuncAttributeMaxDynamicSharedMemorySize, 131072);

    char* p = (char*)d_ws;
    float* Xf = (float*)p; p += R * D * 4;
    unsigned short* XN = (unsigned short*)p; p += R * D * 2;
    unsigned short* QKVb = (unsigned short*)p; p += R * 6144 * 2;
    unsigned short* Warea = (unsigned short*)p;

    unsigned short* H1d = QKVb;
    unsigned short* H1t = QKVb + R * 2048;
    unsigned short* Hfin = QKVb + R * 4096;
    unsigned short* DN = XN;
    unsigned short* TN = XN + R * HD;

    unsigned short* Wqkv_b = Warea;
    unsigned short* Wd1_b = Wqkv_b + 9 * DD;
    unsigned short* Wt1_b = Wd1_b + 2 * D * HD;
    unsigned short* Wd2_b = Wt1_b + 2 * D * HD;
    unsigned short* Wt2_b = Wd2_b + 2 * D * HD;
    unsigned short* Wo1_b = Wt2_b + 2 * D * HD;
    if (planAll) {
      for (int n = 0; n < 3; ++n) {
        cvt(Wq_f + n * DD, Wqkv_b + n * 3 * DD + 0 * DD, DD);
        cvt(Wk_f + n * DD, Wqkv_b + n * 3 * DD + 1 * DD, DD);
        cvt(Wv_f + n * DD, Wqkv_b + n * 3 * DD + 2 * DD, DD);
      }
      cvt(Wd1_f, Wd1_b, 2 * D * HD);
      cvt(Wt1_f, Wt1_b, 2 * D * HD);
      cvt(Wd2_f, Wd2_b, 2 * D * HD);
      cvt(Wt2_f, Wt2_b, 2 * D * HD);
      cvt(Wo1_f, Wo1_b, HD * D);
    }

    auto gemm8 = [&](const unsigned short* A, int lda, const unsigned short* B,
                     int N, int K, void* C, int ldc, const float* bias,
                     int relu, int of32, int resadd, const unsigned short* A2,
                     const unsigned short* B2, void* C2, const float* bias2) {
      const int dual = (A2 != nullptr);
      dim3 grid((dual ? 2 : 1) * (N / 256), 32);
      gemm8_kernel<<<grid, dim3(512), 131072, stream>>>(
          A, lda, B, K, C, ldc, bias, relu, of32, resadd, A2, B2, C2, bias2,
          dual);
    };

    for (int n = 0; n < 3; ++n) {
      ln_kernel<2048><<<8192, 256, 0, stream>>>(
          (n == 0) ? (const void*)x_in : (const void*)Xf, 0, 2048,
          aln_g + n * D, aln_b + n * D, XN, 2048);
      const unsigned short* Wqkv;
      if (planAll) {
        Wqkv = Wqkv_b + (size_t)n * 3 * DD;
      } else {
        cvt(Wq_f + n * DD, Warea + 0 * DD, DD);
        cvt(Wk_f + n * DD, Warea + 1 * DD, DD);
        cvt(Wv_f + n * DD, Warea + 2 * DD, DD);
        Wqkv = Warea;
      }
      gemm8(XN, 2048, Wqkv, 6144, 2048, QKVb, 6144, nullptr, 0, 0, 0,
            nullptr, nullptr, nullptr, nullptr);
      attn_glue_kernel<<<8192, 512, 0, stream>>>(
          QKVb, QKVb + 2048, QKVb + 4096, 6144,
          (n == 0) ? (const void*)x_in : (const void*)Xf, 0, Xf, 0,
          (n == 2) ? XN : nullptr,
          (n < 2) ? DN : nullptr, (n < 2) ? TN : nullptr,
          (n < 2) ? lnd_g + n * HD : nullptr, (n < 2) ? lnd_b + n * HD : nullptr,
          (n < 2) ? lnt_g + n * HD : nullptr, (n < 2) ? lnt_b + n * HD : nullptr);

      if (n < 2) {
        const size_t fo = (size_t)n * D * HD;
        const unsigned short *w1d, *w1t, *w2d, *w2t;
        if (planAll) {
          w1d = Wd1_b + fo; w1t = Wt1_b + fo; w2d = Wd2_b + fo; w2t = Wt2_b + fo;
        } else {
          cvt(Wd1_f + fo, Warea + 0 * D * HD, D * HD);
          cvt(Wt1_f + fo, Warea + 1 * D * HD, D * HD);
          cvt(Wd2_f + fo, Warea + 2 * D * HD, D * HD);
          cvt(Wt2_f + fo, Warea + 3 * D * HD, D * HD);
          w1d = Warea; w1t = Warea + D * HD; w2d = Warea + 2 * D * HD;
          w2t = Warea + 3 * D * HD;
        }
        gemm8(DN, 1024, w1d, 2048, 1024, H1d, 2048, bd1 + n * D, 1, 0, 0,
              TN, w1t, H1t, bt1 + n * D);
        gemm8(H1d, 2048, w2d, 1024, 2048, Xf, 2048, bd2 + n * HD, 0, 1, 1,
              H1t, w2t, Xf + HD, bt2 + n * HD);
      }
    }

    // final head
    const unsigned short* Wo1p;
    if (planAll) {
      Wo1p = Wo1_b;
    } else {
      cvt(Wo1_f, Warea, HD * D);
      Wo1p = Warea;
    }
    gemm8(XN, 2048, Wo1p, 1024, 2048, Hfin, 1024, bo1, 1, 0, 0,
          nullptr, nullptr, nullptr, nullptr);
    final_matvec_kernel<<<8192, 256, 0, stream>>>(Hfin, Wo2_f, bo2,
                                                  (float*)d_out);
    return;
  }

  // ======================= legacy fallback path =======================
  const size_t PLB = R * D * 2;
  const size_t XFZ = R * D * 4;
  const size_t SLOT1 = DD * 2;
  const bool planAll = ws_size >= XFZ + 4 * PLB + WALL;
  const bool xIsF32 = planAll || ws_size >= XFZ + 4 * PLB + SLOT1;

  char* p = (char*)d_ws;
  float* Xf = nullptr;
  unsigned short* Xb = nullptr;
  if (xIsF32) { Xf = (float*)p; p += XFZ; } else { Xb = (unsigned short*)p; p += PLB; }
  unsigned short* XN = (unsigned short*)p; p += PLB;
  unsigned short* Qb = (unsigned short*)p; p += PLB;
  unsigned short* Kb = (unsigned short*)p; p += PLB;
  unsigned short* Vb = (unsigned short*)p; p += PLB;
  unsigned short* Warea = (unsigned short*)p;

  void* X = xIsF32 ? (void*)Xf : (void*)Xb;
  const int xres_mode = xIsF32 ? 1 : 2;
  unsigned short* H1 = Qb;
  unsigned short* DN = XN;
  unsigned short* TN = XN + R * HD;
  unsigned short* Hfin = Vb;

  unsigned short* Wq_b = Warea;
  unsigned short* Wk_b = Wq_b + 3 * DD;
  unsigned short* Wv_b = Wk_b + 3 * DD;
  unsigned short* Wd1_b = Wv_b + 3 * DD;
  unsigned short* Wd2_b = Wd1_b + 2 * D * HD;
  unsigned short* Wt1_b = Wd2_b + 2 * D * HD;
  unsigned short* Wt2_b = Wt1_b + 2 * D * HD;
  unsigned short* Wo1_b = Wt2_b + 2 * D * HD;
  if (planAll) {
    cvt(Wq_f, Wq_b, 3 * DD);
    cvt(Wk_f, Wk_b, 3 * DD);
    cvt(Wv_f, Wv_b, 3 * DD);
    cvt(Wd1_f, Wd1_b, 2 * D * HD);
    cvt(Wd2_f, Wd2_b, 2 * D * HD);
    cvt(Wt1_f, Wt1_b, 2 * D * HD);
    cvt(Wt2_f, Wt2_b, 2 * D * HD);
    cvt(Wo1_f, Wo1_b, HD * D);
  }
  auto wbf = [&](const float* src_base, unsigned short* pre_base, size_t off,
                 size_t cnt) -> const unsigned short* {
    if (planAll) return pre_base + off;
    cvt(src_base + off, Warea, (long)cnt);
    return Warea;
  };
  auto gemm = [&](const unsigned short* A, int lda, const unsigned short* B,
                  int N, int K, void* C, int ldc, const float* bias,
                  const void* res, int res_mode, int ldres, int relu, int of32) {
    dim3 grid(N / 128, 8192 / 128);
    gemm_bt_kernel<<<grid, dim3(256), 0, stream>>>(
        A, lda, B, K, C, ldc, bias, res, res_mode, ldres, relu, of32);
  };

  for (int n = 0; n < 3; ++n) {
    const void* lin = (n == 0) ? (const void*)x_in : (const void*)X;
    const int lin_bf16 = (n == 0) ? 0 : (xIsF32 ? 0 : 1);
    ln_kernel<2048><<<8192, 256, 0, stream>>>(lin, lin_bf16, 2048,
                                              aln_g + n * D, aln_b + n * D, XN, 2048);
    const size_t wo = (size_t)n * DD;
    gemm(XN, 2048, wbf(Wq_f, Wq_b, wo, DD), 2048, 2048, Qb, 2048,
         nullptr, nullptr, 0, 0, 0, 0);
    gemm(XN, 2048, wbf(Wk_f, Wk_b, wo, DD), 2048, 2048, Kb, 2048,
         nullptr, nullptr, 0, 0, 0, 0);
    gemm(XN, 2048, wbf(Wv_f, Wv_b, wo, DD), 2048, 2048, Vb, 2048,
         nullptr, nullptr, 0, 0, 0, 0);
    attn_glue_kernel<<<8192, 512, 0, stream>>>(
        Qb, Kb, Vb, 2048, (n == 0) ? (const void*)x_in : (const void*)X,
        (n == 0) ? 0 : (xIsF32 ? 0 : 1), X, xIsF32 ? 0 : 1,
        (n == 2 && xIsF32) ? XN : nullptr,
        nullptr, nullptr, nullptr, nullptr, nullptr, nullptr);

    if (n < 2) {
      const size_t fo = (size_t)n * D * HD;
      ln_kernel<1024><<<8192, 256, 0, stream>>>(X, !xIsF32, 2048,
                                                lnd_g + n * HD, lnd_b + n * HD, DN, 1024);
      const void* Xt = xIsF32 ? (const void*)(Xf + HD) : (const void*)(Xb + HD);
      ln_kernel<1024><<<8192, 256, 0, stream>>>(Xt, !xIsF32, 2048,
                                                lnt_g + n * HD, lnt_b + n * HD, TN, 1024);
      void* Xd2 = X;
      void* Xt2 = xIsF32 ? (void*)(Xf + HD) : (void*)(Xb + HD);
      gemm(DN, 1024, wbf(Wd1_f, Wd1_b, fo, D * HD), 2048, 1024, H1, 2048,
           bd1 + n * D, nullptr, 0, 0, 1, 0);
      gemm(H1, 2048, wbf(Wd2_f, Wd2_b, fo, D * HD), 1024, 2048, Xd2, 2048,
           bd2 + n * HD, Xd2, xres_mode, 2048, 0, xIsF32 ? 1 : 0);
      gemm(TN, 1024, wbf(Wt1_f, Wt1_b, fo, D * HD), 2048, 1024, H1, 2048,
           bt1 + n * D, nullptr, 0, 0, 1, 0);
      gemm(H1, 2048, wbf(Wt2_f, Wt2_b, fo, D * HD), 1024, 2048, Xt2, 2048,
           bt2 + n * HD, Xt2, xres_mode, 2048, 0, xIsF32 ? 1 : 0);
    }
  }

  const unsigned short* Afin = xIsF32 ? XN : Xb;
  gemm(Afin, 2048, wbf(Wo1_f, Wo1_b, 0, HD * D), 1024, 2048, Hfin, 1024,
       bo1, nullptr, 0, 0, 1, 0);
  final_matvec_kernel<<<8192, 256, 0, stream>>>(Hfin, Wo2_f, bo2, (float*)d_out);
}

// Round 10
// 1322.286 us; speedup vs baseline: 2.2072x; 1.0140x over previous
//
#include <hip/hip_runtime.h>
#include <stdint.h>

// ---------------------------------------------------------------------------
// PairwiseAttentionLinear — fp32 in/out on device.
// Round 10 (additive over r7): T1 bijective XCD block-swizzle in gemm8,
// phase-A LGKM(8) cap, dead-X-write skip in last attn_glue, single
// multi-segment weight-cvt dispatch. gemm8 K-loop schedule = r7 (stable best;
// 5 scheduling variants measured neutral, MFMA pipe at floor).
// ---------------------------------------------------------------------------

typedef __bf16 bf16x8 __attribute__((ext_vector_type(8)));
typedef float f32x4 __attribute__((ext_vector_type(4)));

static __device__ __forceinline__ float bf2f(unsigned short u) {
  unsigned int x = ((unsigned int)u) << 16;
  float f;
  __builtin_memcpy(&f, &x, 4);
  return f;
}
static __device__ __forceinline__ unsigned short f2bf(float f) {
  unsigned int x;
  __builtin_memcpy(&x, &f, 4);
  x += 0x7fffu + ((x >> 16) & 1u);  // RNE
  return (unsigned short)(x >> 16);
}

static __device__ __forceinline__ void gload_lds16(const void* g, void* l) {
  __builtin_amdgcn_global_load_lds(
      (const __attribute__((address_space(1))) unsigned int*)g,
      (__attribute__((address_space(3))) unsigned int*)l, 16, 0, 0);
}

__global__ __launch_bounds__(256) void cvt_kernel(
    const float* __restrict__ in, unsigned short* __restrict__ out, long n) {
  const long i = ((long)blockIdx.x * 256 + threadIdx.x) * 4;
  if (i + 3 < n) {
    float4 f = *(const float4*)(in + i);
    *(ushort4*)(out + i) = make_ushort4(f2bf(f.x), f2bf(f.y), f2bf(f.z), f2bf(f.w));
  }
}

// Multi-segment fp32->bf16: all segment lengths are multiples of 1024, so a
// 256-thread block (1024 elems) never straddles a segment boundary.
#define MAXSEG 14
struct CvtArgs {
  const float* src[MAXSEG];
  unsigned short* dst[MAXSEG];
  long pfx[MAXSEG + 1];
  int ns;
};
__global__ __launch_bounds__(256) void cvt_multi_kernel(CvtArgs a) {
  const long i = ((long)blockIdx.x * 256 + threadIdx.x) * 4;
  int s = 0;
  while (s + 1 < a.ns && i >= a.pfx[s + 1]) ++s;
  const long off = i - a.pfx[s];
  float4 f = *(const float4*)(a.src[s] + off);
  *(ushort4*)(a.dst[s] + off) =
      make_ushort4(f2bf(f.x), f2bf(f.y), f2bf(f.z), f2bf(f.w));
}

// ---------------------------------------------------------------------------
// gemm8: 256x256 tile, BK=64, 512 thr (8 waves, 2Mx4N), per-wave 128x64.
// LDS 128 KiB dbuf (prefetch distance 2). T2 swizzle byte ^= ((row&7)<<4)
// via pre-swizzled global src + swizzled ds_read. Phases A-D (r7 schedule,
// kk-outer MFMA). NEW: T1 bijective XCD-chunked block swizzle (m204 form).
// ---------------------------------------------------------------------------
#define BARRIER __builtin_amdgcn_s_barrier()
#define LGKM(N)                                                     \
  do {                                                              \
    asm volatile("s_waitcnt lgkmcnt(" #N ")" ::: "memory");         \
    __builtin_amdgcn_sched_barrier(0);                              \
  } while (0)
#define VMC(N)                                                      \
  do {                                                              \
    asm volatile("s_waitcnt vmcnt(" #N ")" ::: "memory");           \
    __builtin_amdgcn_sched_barrier(0);                              \
  } while (0)

__global__ __launch_bounds__(512, 2) void gemm8_kernel(
    const unsigned short* __restrict__ A, int lda,
    const unsigned short* __restrict__ B, int K,
    void* __restrict__ Cp, int ldc, const float* __restrict__ bias,
    int relu, int out_f32, int resadd,
    const unsigned short* __restrict__ A2, const unsigned short* __restrict__ B2,
    void* __restrict__ C2p, const float* __restrict__ bias2, int dual) {
  extern __shared__ __align__(16) char smem[];  // 131072 B

  const int tid = threadIdx.x;
  const int lane = tid & 63;
  const int w = tid >> 6;
  const int wm = w >> 2;  // 0..1
  const int wn = w & 3;   // 0..3

  // T1: bijective XCD-chunked remap (m204). Dispatch round-robins blocks
  // across 8 XCDs; give each XCD a contiguous chunk of row-major tile space
  // so neighboring tiles (sharing A-panels) hit the same per-XCD L2.
  const int gx = (int)gridDim.x;
  const int nwg = gx * (int)gridDim.y;
  const int orig = (int)blockIdx.y * gx + (int)blockIdx.x;
  const int qch = nwg >> 3, rch = nwg & 7, xcd = orig & 7, io = orig >> 3;
  const int wgid =
      (xcd < rch ? xcd * (qch + 1) : rch * (qch + 1) + (xcd - rch) * qch) + io;
  const int bx = wgid % gx;
  const int by = wgid / gx;
  const long brow = (long)by * 256;

  const unsigned short* Ap = A;
  const unsigned short* Bp = B;
  const float* bi = bias;
  void* Cq = Cp;
  long bcol;
  if (dual && bx >= (gx >> 1)) {
    Ap = A2; Bp = B2; bi = bias2; Cq = C2p;
    bcol = (long)(bx - (gx >> 1)) * 256;
  } else {
    bcol = (long)bx * 256;
  }

  const int NT = K >> 6;  // K-tiles of 64

  // ---- staging addressing, hoisted
  const int lrA = tid >> 3;
  const int scb = ((tid & 7) * 16) ^ (((tid >> 3) & 7) << 4);  // pre-swz src
  const unsigned wb = (unsigned)(tid & ~63) * 16;
  const long ldab = (long)lda * 2;
  const long ldbb = (long)K * 2;
  const char* gA = (const char*)Ap + (brow + lrA) * ldab + scb;
  const char* gB = (const char*)Bp + (bcol + lrA) * ldbb + scb;
  const long a64 = 64 * ldab, a128 = 128 * ldab, a192 = 192 * ldab;
  const long b64 = 64 * ldbb, b128 = 128 * ldbb, b192 = 192 * ldbb;

#define STAGE_A(bb, off)                                        \
  do {                                                          \
    gload_lds16(gA + (off), smem + (bb) + wb);                  \
    gload_lds16(gA + a64 + (off), smem + (bb) + 8192 + wb);     \
    gload_lds16(gA + a128 + (off), smem + (bb) + 16384 + wb);   \
    gload_lds16(gA + a192 + (off), smem + (bb) + 24576 + wb);   \
  } while (0)
#define STAGE_B(bb, off)                                        \
  do {                                                          \
    gload_lds16(gB + (off), smem + (bb) + 32768 + wb);          \
    gload_lds16(gB + b64 + (off), smem + (bb) + 40960 + wb);    \
    gload_lds16(gB + b128 + (off), smem + (bb) + 49152 + wb);   \
    gload_lds16(gB + b192 + (off), smem + (bb) + 57344 + wb);   \
  } while (0)

  f32x4 acc[8][4];
  const f32x4 fz = {0.f, 0.f, 0.f, 0.f};
#pragma unroll
  for (int m = 0; m < 8; ++m)
#pragma unroll
    for (int n = 0; n < 4; ++n) acc[m][n] = fz;

  const int frow = lane & 15;
  const int fkb = (lane >> 4) * 16;  // k-byte within 64-col row
  const int fswz = (lane & 7) << 4;  // T2 read-side swizzle

#define RDA(dst, CB, M, KK)                                                   \
  dst = *(const bf16x8*)(smem + (CB) + (wm * 128 + (M) * 16 + frow) * 128 +   \
                         (((KK) * 64 + fkb) ^ fswz))
#define RDB(dst, CB, N, KK)                                                   \
  dst = *(const bf16x8*)(smem + (CB) + 32768 +                                \
                         (wn * 64 + (N) * 16 + frow) * 128 +                  \
                         (((KK) * 64 + fkb) ^ fswz))

  // 8 MFMAs, kk OUTER (per-acc reuse distance 4)
#define MM8(AF, MA, BF, NA, MO, NO)                                           \
  do {                                                                        \
    _Pragma("unroll") for (int kk = 0; kk < 2; ++kk)                          \
    _Pragma("unroll") for (int mm = 0; mm < 2; ++mm)                          \
    _Pragma("unroll") for (int nn = 0; nn < 2; ++nn)                          \
        acc[(MO) + mm][(NO) + nn] = __builtin_amdgcn_mfma_f32_16x16x32_bf16(  \
            AF[(MA) + mm][kk], BF[(NA) + nn][kk], acc[(MO) + mm][(NO) + nn],  \
            0, 0, 0);                                                         \
  } while (0)
#define MM8N(AF, BF, NB, NO)                                                  \
  do {                                                                        \
    _Pragma("unroll") for (int kk = 0; kk < 2; ++kk)                          \
    _Pragma("unroll") for (int mm = 0; mm < 4; ++mm)                          \
        acc[mm][(NO)] = __builtin_amdgcn_mfma_f32_16x16x32_bf16(              \
            AF[mm][kk], BF[(NB)][kk], acc[mm][(NO)], 0, 0, 0);                \
  } while (0)

  bf16x8 afL[4][2], afH[4][2], bfvL[2][2], bfvH[2][2];

  // ---- prologue: stage tiles 0 (buf0) and 1 (buf1); wait tile 0
  STAGE_A(0, 0);
  STAGE_B(0, 0);
  STAGE_A(65536, 128);
  STAGE_B(65536, 128);
  VMC(8);
  BARRIER;
  long soff = 256;  // staging byte-offset of tile t+2

#define TILE_IT(T, CB)                                                        \
  do {                                                                        \
    /* phase A: read bfvL(4)+afL(8) ; LGKM cap ; Q0 */                        \
    RDB(bfvL[0][0], CB, 0, 0); RDB(bfvL[0][1], CB, 0, 1);                     \
    RDB(bfvL[1][0], CB, 1, 0); RDB(bfvL[1][1], CB, 1, 1);                     \
    RDA(afL[0][0], CB, 0, 0); RDA(afL[0][1], CB, 0, 1);                       \
    RDA(afL[1][0], CB, 1, 0); RDA(afL[1][1], CB, 1, 1);                       \
    RDA(afL[2][0], CB, 2, 0); RDA(afL[2][1], CB, 2, 1);                       \
    RDA(afL[3][0], CB, 3, 0); RDA(afL[3][1], CB, 3, 1);                       \
    LGKM(8); /* cap in-flight before barrier (m201 knob) */                   \
    BARRIER;                                                                  \
    LGKM(0);                                                                  \
    __builtin_amdgcn_s_setprio(1);                                            \
    MM8(afL, 0, bfvL, 0, 0, 0);                                               \
    MM8(afL, 2, bfvL, 0, 2, 0);                                               \
    __builtin_amdgcn_s_setprio(0);                                            \
    BARRIER;                                                                  \
    /* phase B: read bfvH(4) ; Q1 */                                          \
    RDB(bfvH[0][0], CB, 2, 0); RDB(bfvH[0][1], CB, 2, 1);                     \
    RDB(bfvH[1][0], CB, 3, 0); RDB(bfvH[1][1], CB, 3, 1);                     \
    BARRIER;                                                                  \
    LGKM(0);                                                                  \
    __builtin_amdgcn_s_setprio(1);                                            \
    MM8N(afL, bfvH, 0, 2);                                                    \
    MM8N(afL, bfvH, 1, 3);                                                    \
    __builtin_amdgcn_s_setprio(0);                                            \
    BARRIER;                                                                  \
    /* all B-region reads of tile T drained (end-of-B barrier) */             \
    /* phase C: read afH(8) ; stage B(T+2) ; Q2 */                            \
    RDA(afH[0][0], CB, 4, 0); RDA(afH[0][1], CB, 4, 1);                       \
    RDA(afH[1][0], CB, 5, 0); RDA(afH[1][1], CB, 5, 1);                       \
    RDA(afH[2][0], CB, 6, 0); RDA(afH[2][1], CB, 6, 1);                       \
    RDA(afH[3][0], CB, 7, 0); RDA(afH[3][1], CB, 7, 1);                       \
    if ((T) + 2 < NT) STAGE_B(CB, soff);                                      \
    BARRIER;                                                                  \
    LGKM(0);                                                                  \
    __builtin_amdgcn_s_setprio(1);                                            \
    MM8(afH, 0, bfvL, 0, 4, 0);                                               \
    MM8(afH, 2, bfvL, 0, 6, 0);                                               \
    __builtin_amdgcn_s_setprio(0);                                            \
    BARRIER;                                                                  \
    /* all A-region reads of tile T drained (end-of-C barrier) */             \
    /* phase D: stage A(T+2); counted vmcnt; Q3 */                            \
    if ((T) + 2 < NT) {                                                       \
      STAGE_A(CB, soff);                                                      \
      VMC(8); /* tile T+1 fully landed */                                     \
    } else {                                                                  \
      VMC(0); /* tail drain */                                                \
    }                                                                         \
    BARRIER;                                                                  \
    __builtin_amdgcn_s_setprio(1);                                            \
    MM8(afH, 0, bfvH, 0, 4, 2);                                               \
    MM8(afH, 2, bfvH, 0, 6, 2);                                               \
    __builtin_amdgcn_s_setprio(0);                                            \
    BARRIER;                                                                  \
    soff += 128;                                                              \
  } while (0)

  for (int t = 0; t < NT; t += 2) {
    TILE_IT(t, 0);
    TILE_IT(t + 1, 65536);
  }

  // ---- epilogue: C/D layout col=lane&15, row=(lane>>4)*4+reg [m89]
  const long rb0 = brow + wm * 128 + (lane >> 4) * 4;
  const long cb0 = bcol + wn * 64 + (lane & 15);
#pragma unroll
  for (int m = 0; m < 8; ++m) {
#pragma unroll
    for (int n = 0; n < 4; ++n) {
      const long col = cb0 + n * 16;
      const float bv = bi ? bi[col] : 0.f;
#pragma unroll
      for (int j = 0; j < 4; ++j) {
        const long r = rb0 + m * 16 + j;
        float v = acc[m][n][j] + bv;
        if (relu) v = fmaxf(v, 0.f);
        if (out_f32) {
          float* cp = (float*)Cq + r * (long)ldc + col;
          if (resadd) v += *cp;
          *cp = v;
        } else {
          ((unsigned short*)Cq)[r * (long)ldc + col] = f2bf(v);
        }
      }
    }
  }
#undef TILE_IT
#undef STAGE_A
#undef STAGE_B
#undef RDA
#undef RDB
#undef MM8
#undef MM8N
}

// ---------------------------------------------------------------------------
// Legacy 128x128 GEMM — fallback path only.
// ---------------------------------------------------------------------------
__global__ __launch_bounds__(256) void gemm_bt_kernel(
    const unsigned short* __restrict__ A, int lda,
    const unsigned short* __restrict__ B, int K,
    void* __restrict__ Cp, int ldc,
    const float* __restrict__ bias,
    const void* __restrict__ res, int res_mode, int ldres,
    int relu, int out_f32) {
  __shared__ __align__(16) unsigned short As[128 * 32];
  __shared__ __align__(16) unsigned short Bs[128 * 32];

  const int t = threadIdx.x;
  const int lane = t & 63;
  const int w = t >> 6;
  const int wr = (w >> 1) * 64;
  const int wc = (w & 1) * 64;
  const long brow = (long)blockIdx.y * 128;
  const long bcol = (long)blockIdx.x * 128;

  const int srow = lane >> 2;
  const int scol = (lane & 3) * 8;
  const unsigned short* Ab = A + (brow + w * 32 + srow) * (long)lda + scol;
  const unsigned short* Bb = B + (bcol + w * 32 + srow) * (long)K + scol;
  unsigned short* Asb = &As[(w * 32) * 32];
  unsigned short* Bsb = &Bs[(w * 32) * 32];

  f32x4 acc[4][4];
  const f32x4 fzero = {0.f, 0.f, 0.f, 0.f};
#pragma unroll
  for (int m = 0; m < 4; ++m)
#pragma unroll
    for (int n = 0; n < 4; ++n) acc[m][n] = fzero;

  const int fr = lane & 15;
  const int fk = (lane >> 4) * 8;

  for (int kt = 0; kt < K; kt += 32) {
    gload_lds16(Ab + kt, Asb);
    gload_lds16(Ab + 16 * (long)lda + kt, Asb + 16 * 32);
    gload_lds16(Bb + kt, Bsb);
    gload_lds16(Bb + 16 * (long)K + kt, Bsb + 16 * 32);
    __syncthreads();

    bf16x8 af[4], bfv[4];
#pragma unroll
    for (int m = 0; m < 4; ++m)
      af[m] = *(const bf16x8*)&As[(wr + m * 16 + fr) * 32 + fk];
#pragma unroll
    for (int n = 0; n < 4; ++n)
      bfv[n] = *(const bf16x8*)&Bs[(wc + n * 16 + fr) * 32 + fk];
#pragma unroll
    for (int m = 0; m < 4; ++m)
#pragma unroll
      for (int n = 0; n < 4; ++n)
        acc[m][n] = __builtin_amdgcn_mfma_f32_16x16x32_bf16(af[m], bfv[n],
                                                            acc[m][n], 0, 0, 0);
    __syncthreads();
  }

  const long rbase = brow + wr + (lane >> 4) * 4;
#pragma unroll
  for (int m = 0; m < 4; ++m) {
#pragma unroll
    for (int n = 0; n < 4; ++n) {
      const long col = bcol + wc + n * 16 + fr;
      const float bv = bias ? bias[col] : 0.f;
#pragma unroll
      for (int j = 0; j < 4; ++j) {
        const long r = rbase + m * 16 + j;
        float v = acc[m][n][j] + bv;
        if (relu) v = fmaxf(v, 0.f);
        if (res_mode == 1)
          v += ((const float*)res)[r * (long)ldres + col];
        else if (res_mode == 2)
          v += bf2f(((const unsigned short*)res)[r * (long)ldres + col]);
        if (out_f32)
          ((float*)Cp)[r * (long)ldc + col] = v;
        else
          ((unsigned short*)Cp)[r * (long)ldc + col] = f2bf(v);
      }
    }
  }
}

// ---------------------------------------------------------------------------
template <int L>
__global__ __launch_bounds__(256) void ln_kernel(
    const void* __restrict__ inp, int in_bf16, int ldin,
    const float* __restrict__ g, const float* __restrict__ b,
    unsigned short* __restrict__ outp, int ldout) {
  constexpr int VEC = L / 256;
  const long row = blockIdx.x;
  const int t = threadIdx.x;
  float v[VEC];
  if (in_bf16) {
    const unsigned short* p = (const unsigned short*)inp + row * (long)ldin + t * VEC;
#pragma unroll
    for (int i = 0; i < VEC; i += 4) {
      ushort4 u = *(const ushort4*)(p + i);
      v[i] = bf2f(u.x); v[i + 1] = bf2f(u.y); v[i + 2] = bf2f(u.z); v[i + 3] = bf2f(u.w);
    }
  } else {
    const float* p = (const float*)inp + row * (long)ldin + t * VEC;
#pragma unroll
    for (int i = 0; i < VEC; i += 4) {
      float4 f = *(const float4*)(p + i);
      v[i] = f.x; v[i + 1] = f.y; v[i + 2] = f.z; v[i + 3] = f.w;
    }
  }
  float s = 0.f, sq = 0.f;
#pragma unroll
  for (int i = 0; i < VEC; ++i) { s += v[i]; sq += v[i] * v[i]; }
#pragma unroll
  for (int off = 32; off; off >>= 1) {
    s += __shfl_xor(s, off, 64);
    sq += __shfl_xor(sq, off, 64);
  }
  __shared__ float red[8];
  if ((t & 63) == 0) { red[t >> 6] = s; red[4 + (t >> 6)] = sq; }
  __syncthreads();
  s = red[0] + red[1] + red[2] + red[3];
  sq = red[4] + red[5] + red[6] + red[7];
  const float mean = s * (1.f / L);
  const float var = sq * (1.f / L) - mean * mean;
  const float rstd = rsqrtf(var + 1e-6f);
  unsigned short* op = outp + row * (long)ldout + t * VEC;
  const float* gp = g + t * VEC;
  const float* bp = b + t * VEC;
#pragma unroll
  for (int i = 0; i < VEC; i += 4) {
    float4 gg = *(const float4*)(gp + i);
    float4 bb = *(const float4*)(bp + i);
    *(ushort4*)(op + i) = make_ushort4(
        f2bf((v[i + 0] - mean) * rstd * gg.x + bb.x),
        f2bf((v[i + 1] - mean) * rstd * gg.y + bb.y),
        f2bf((v[i + 2] - mean) * rstd * gg.z + bb.z),
        f2bf((v[i + 3] - mean) * rstd * gg.w + bb.w));
  }
}

// ---------------------------------------------------------------------------
// Pairwise attention glue + optional fused d/t LayerNorms. Xout nullable
// (last layer needs only the bf16 copy for the final head).
// ---------------------------------------------------------------------------
__global__ __launch_bounds__(512) void attn_glue_kernel(
    const unsigned short* __restrict__ Q, const unsigned short* __restrict__ Kq,
    const unsigned short* __restrict__ V, int ld, const void* __restrict__ Xres,
    int res_bf16, void* __restrict__ Xout, int out_bf16,
    unsigned short* __restrict__ Xout_bf,
    unsigned short* __restrict__ DNp, unsigned short* __restrict__ TNp,
    const float* __restrict__ lnd_g, const float* __restrict__ lnd_b,
    const float* __restrict__ lnt_g, const float* __restrict__ lnt_b) {
  const long row = blockIdx.x;
  const int h = threadIdx.x >> 6;
  const int lane = threadIdx.x & 63;
  const long qbase = row * (long)ld + h * 256;
  const long xbase = row * 2048 + h * 256;
  const int d = lane * 2;

  ushort2 q0 = *(const ushort2*)&Q[qbase + d];
  ushort2 q1 = *(const ushort2*)&Q[qbase + 128 + d];
  ushort2 k0 = *(const ushort2*)&Kq[qbase + d];
  ushort2 k1 = *(const ushort2*)&Kq[qbase + 128 + d];
  ushort2 v0 = *(const ushort2*)&V[qbase + d];
  ushort2 v1 = *(const ushort2*)&V[qbase + 128 + d];

  const float q0x = bf2f(q0.x), q0y = bf2f(q0.y);
  const float q1x = bf2f(q1.x), q1y = bf2f(q1.y);
  const float k0x = bf2f(k0.x), k0y = bf2f(k0.y);
  const float k1x = bf2f(k1.x), k1y = bf2f(k1.y);

  float s00 = q0x * k0x + q0y * k0y;
  float s01 = q0x * k1x + q0y * k1y;
  float s10 = q1x * k0x + q1y * k0y;
  float s11 = q1x * k1x + q1y * k1y;
#pragma unroll
  for (int off = 32; off; off >>= 1) {
    s00 += __shfl_xor(s00, off, 64);
    s01 += __shfl_xor(s01, off, 64);
    s10 += __shfl_xor(s10, off, 64);
    s11 += __shfl_xor(s11, off, 64);
  }
  const float SC = 0.088388347648318447f;  // 1/sqrt(128)
  s00 *= SC; s01 *= SC; s10 *= SC; s11 *= SC;
  const float m0 = fmaxf(s00, s01), m1 = fmaxf(s10, s11);
  const float e00 = __expf(s00 - m0), e01 = __expf(s01 - m0);
  const float e10 = __expf(s10 - m1), e11 = __expf(s11 - m1);
  const float i0 = 1.f / (e00 + e01), i1 = 1.f / (e10 + e11);
  const float a00 = e00 * i0, a01 = e01 * i0;
  const float a10 = e10 * i1, a11 = e11 * i1;

  const float v0x = bf2f(v0.x), v0y = bf2f(v0.y);
  const float v1x = bf2f(v1.x), v1y = bf2f(v1.y);
  float o0x = a00 * v0x + a01 * v1x, o0y = a00 * v0y + a01 * v1y;
  float o1x = a10 * v0x + a11 * v1x, o1y = a10 * v0y + a11 * v1y;

  if (res_bf16) {
    const unsigned short* xr = (const unsigned short*)Xres + xbase;
    ushort2 ra = *(const ushort2*)&xr[d];
    ushort2 rb = *(const ushort2*)&xr[128 + d];
    o0x += bf2f(ra.x); o0y += bf2f(ra.y); o1x += bf2f(rb.x); o1y += bf2f(rb.y);
  } else {
    const float* xr = (const float*)Xres + xbase;
    float2 ra = *(const float2*)&xr[d];
    float2 rb = *(const float2*)&xr[128 + d];
    o0x += ra.x; o0y += ra.y; o1x += rb.x; o1y += rb.y;
  }
  if (Xout) {
    if (out_bf16) {
      unsigned short* xo = (unsigned short*)Xout + xbase;
      *(ushort2*)&xo[d] = make_ushort2(f2bf(o0x), f2bf(o0y));
      *(ushort2*)&xo[128 + d] = make_ushort2(f2bf(o1x), f2bf(o1y));
    } else {
      float* xo = (float*)Xout + xbase;
      *(float2*)&xo[d] = make_float2(o0x, o0y);
      *(float2*)&xo[128 + d] = make_float2(o1x, o1y);
    }
  }
  if (Xout_bf) {
    unsigned short* xb = Xout_bf + xbase;
    *(ushort2*)&xb[d] = make_ushort2(f2bf(o0x), f2bf(o0y));
    *(ushort2*)&xb[128 + d] = make_ushort2(f2bf(o1x), f2bf(o1y));
  }

  // ---- fused d/t LayerNorm over the two 1024-halves (uniform branch) ----
  if (DNp) {
    float s4 = o0x + o0y + o1x + o1y;
    float q4 = o0x * o0x + o0y * o0y + o1x * o1x + o1y * o1y;
#pragma unroll
    for (int off = 32; off; off >>= 1) {
      s4 += __shfl_xor(s4, off, 64);
      q4 += __shfl_xor(q4, off, 64);
    }
    __shared__ float redS[8], redQ[8];
    if (lane == 0) { redS[h] = s4; redQ[h] = q4; }
    __syncthreads();
    const int b4 = (h >> 2) * 4;
    const float S = redS[b4] + redS[b4 + 1] + redS[b4 + 2] + redS[b4 + 3];
    const float Qs = redQ[b4] + redQ[b4 + 1] + redQ[b4 + 2] + redQ[b4 + 3];
    const float mean = S * (1.f / 1024.f);
    const float var = Qs * (1.f / 1024.f) - mean * mean;
    const float rstd = rsqrtf(var + 1e-6f);
    const float* gp = (h < 4) ? lnd_g : lnt_g;
    const float* bp = (h < 4) ? lnd_b : lnt_b;
    unsigned short* dst = ((h < 4) ? DNp : TNp) + row * 1024;
    const int hc = (h & 3) * 256 + d;
    float2 g0 = *(const float2*)&gp[hc];
    float2 b0 = *(const float2*)&bp[hc];
    *(ushort2*)&dst[hc] = make_ushort2(f2bf((o0x - mean) * rstd * g0.x + b0.x),
                                       f2bf((o0y - mean) * rstd * g0.y + b0.y));
    float2 g1 = *(const float2*)&gp[hc + 128];
    float2 b1 = *(const float2*)&bp[hc + 128];
    *(ushort2*)&dst[hc + 128] =
        make_ushort2(f2bf((o1x - mean) * rstd * g1.x + b1.x),
                     f2bf((o1y - mean) * rstd * g1.y + b1.y));
  }
}

__global__ __launch_bounds__(256) void final_matvec_kernel(
    const unsigned short* __restrict__ Hm, const float* __restrict__ wv,
    const float* __restrict__ b2, float* __restrict__ outp) {
  const long row = blockIdx.x;
  const int t = threadIdx.x;
  ushort4 hv = *(const ushort4*)&Hm[row * 1024 + t * 4];
  float4 wq = *(const float4*)&wv[t * 4];
  float s = bf2f(hv.x) * wq.x + bf2f(hv.y) * wq.y +
            bf2f(hv.z) * wq.z + bf2f(hv.w) * wq.w;
#pragma unroll
  for (int off = 32; off; off >>= 1) s += __shfl_xor(s, off, 64);
  __shared__ float red[4];
  if ((t & 63) == 0) red[t >> 6] = s;
  __syncthreads();
  if (t == 0) outp[row] = red[0] + red[1] + red[2] + red[3] + b2[0];
}

// ---------------------------------------------------------------------------
extern "C" void kernel_launch(void* const* d_in, const int* in_sizes, int n_in,
                              void* d_out, int out_size, void* d_ws,
                              size_t ws_size, hipStream_t stream) {
  const float* x_in = (const float*)d_in[0];
  const float* aln_g = (const float*)d_in[1];
  const float* aln_b = (const float*)d_in[2];
  const float* Wq_f = (const float*)d_in[3];
  const float* Wk_f = (const float*)d_in[4];
  const float* Wv_f = (const float*)d_in[5];
  const float* lnd_g = (const float*)d_in[6];
  const float* lnd_b = (const float*)d_in[7];
  const float* lnt_g = (const float*)d_in[8];
  const float* lnt_b = (const float*)d_in[9];
  const float* Wd1_f = (const float*)d_in[10];
  const float* bd1 = (const float*)d_in[11];
  const float* Wd2_f = (const float*)d_in[12];
  const float* bd2 = (const float*)d_in[13];
  const float* Wt1_f = (const float*)d_in[14];
  const float* bt1 = (const float*)d_in[15];
  const float* Wt2_f = (const float*)d_in[16];
  const float* bt2 = (const float*)d_in[17];
  const float* Wo1_f = (const float*)d_in[18];
  const float* bo1 = (const float*)d_in[19];
  const float* Wo2_f = (const float*)d_in[20];
  const float* bo2 = (const float*)d_in[21];

  const size_t R = 8192, D = 2048, HD = 1024;
  const size_t DD = D * D;
  const size_t WALL = (3 * 3 * DD + 4 * 2 * D * HD + HD * D) * 2;  // 108 MiB
  const size_t SLOT = 3 * DD * 2;                                  // 24 MiB
  const size_t ACT = R * D * 4 + R * D * 2 + R * 6144 * 2;         // 192 MiB

  auto cvt = [&](const float* src, unsigned short* dst, long n) {
    cvt_kernel<<<dim3((unsigned)(n / 1024)), dim3(256), 0, stream>>>(src, dst, n);
  };

  if (ws_size >= ACT + SLOT) {
    // ===================== fast path (8-phase GEMMs) =====================
    const bool planAll = ws_size >= ACT + WALL;
    hipFuncSetAttribute(reinterpret_cast<const void*>(gemm8_kernel),
                        hipFuncAttributeMaxDynamicSharedMemorySize, 131072);

    char* p = (char*)d_ws;
    float* Xf = (float*)p; p += R * D * 4;
    unsigned short* XN = (unsigned short*)p; p += R * D * 2;
    unsigned short* QKVb = (unsigned short*)p; p += R * 6144 * 2;
    unsigned short* Warea = (unsigned short*)p;

    unsigned short* H1d = QKVb;
    unsigned short* H1t = QKVb + R * 2048;
    unsigned short* Hfin = QKVb + R * 4096;
    unsigned short* DN = XN;
    unsigned short* TN = XN + R * HD;

    unsigned short* Wqkv_b = Warea;
    unsigned short* Wd1_b = Wqkv_b + 9 * DD;
    unsigned short* Wt1_b = Wd1_b + 2 * D * HD;
    unsigned short* Wd2_b = Wt1_b + 2 * D * HD;
    unsigned short* Wt2_b = Wd2_b + 2 * D * HD;
    unsigned short* Wo1_b = Wt2_b + 2 * D * HD;
    if (planAll) {
      // one multi-segment cvt dispatch for all 14 weight conversions
      CvtArgs ca;
      int s = 0;
      long pfx = 0;
      auto add = [&](const float* src, unsigned short* dst, long n) {
        ca.src[s] = src; ca.dst[s] = dst; ca.pfx[s] = pfx; pfx += n; ++s;
      };
      for (int n = 0; n < 3; ++n) {
        add(Wq_f + n * DD, Wqkv_b + n * 3 * DD + 0 * DD, (long)DD);
        add(Wk_f + n * DD, Wqkv_b + n * 3 * DD + 1 * DD, (long)DD);
        add(Wv_f + n * DD, Wqkv_b + n * 3 * DD + 2 * DD, (long)DD);
      }
      add(Wd1_f, Wd1_b, (long)(2 * D * HD));
      add(Wt1_f, Wt1_b, (long)(2 * D * HD));
      add(Wd2_f, Wd2_b, (long)(2 * D * HD));
      add(Wt2_f, Wt2_b, (long)(2 * D * HD));
      add(Wo1_f, Wo1_b, (long)(HD * D));
      ca.pfx[s] = pfx;
      ca.ns = s;
      cvt_multi_kernel<<<dim3((unsigned)(pfx / 1024)), dim3(256), 0, stream>>>(ca);
    }

    auto gemm8 = [&](const unsigned short* A, int lda, const unsigned short* B,
                     int N, int K, void* C, int ldc, const float* bias,
                     int relu, int of32, int resadd, const unsigned short* A2,
                     const unsigned short* B2, void* C2, const float* bias2) {
      const int dual = (A2 != nullptr);
      dim3 grid((dual ? 2 : 1) * (N / 256), 32);
      gemm8_kernel<<<grid, dim3(512), 131072, stream>>>(
          A, lda, B, K, C, ldc, bias, relu, of32, resadd, A2, B2, C2, bias2,
          dual);
    };

    for (int n = 0; n < 3; ++n) {
      ln_kernel<2048><<<8192, 256, 0, stream>>>(
          (n == 0) ? (const void*)x_in : (const void*)Xf, 0, 2048,
          aln_g + n * D, aln_b + n * D, XN, 2048);
      const unsigned short* Wqkv;
      if (planAll) {
        Wqkv = Wqkv_b + (size_t)n * 3 * DD;
      } else {
        cvt(Wq_f + n * DD, Warea + 0 * DD, DD);
        cvt(Wk_f + n * DD, Warea + 1 * DD, DD);
        cvt(Wv_f + n * DD, Warea + 2 * DD, DD);
        Wqkv = Warea;
      }
      gemm8(XN, 2048, Wqkv, 6144, 2048, QKVb, 6144, nullptr, 0, 0, 0,
            nullptr, nullptr, nullptr, nullptr);
      // n<2: write fp32 X + fused d/t LN. n==2: only bf16 copy for final head.
      attn_glue_kernel<<<8192, 512, 0, stream>>>(
          QKVb, QKVb + 2048, QKVb + 4096, 6144,
          (n == 0) ? (const void*)x_in : (const void*)Xf, 0,
          (n < 2) ? (void*)Xf : nullptr, 0,
          (n == 2) ? XN : nullptr,
          (n < 2) ? DN : nullptr, (n < 2) ? TN : nullptr,
          (n < 2) ? lnd_g + n * HD : nullptr, (n < 2) ? lnd_b + n * HD : nullptr,
          (n < 2) ? lnt_g + n * HD : nullptr, (n < 2) ? lnt_b + n * HD : nullptr);

      if (n < 2) {
        const size_t fo = (size_t)n * D * HD;
        const unsigned short *w1d, *w1t, *w2d, *w2t;
        if (planAll) {
          w1d = Wd1_b + fo; w1t = Wt1_b + fo; w2d = Wd2_b + fo; w2t = Wt2_b + fo;
        } else {
          cvt(Wd1_f + fo, Warea + 0 * D * HD, D * HD);
          cvt(Wt1_f + fo, Warea + 1 * D * HD, D * HD);
          cvt(Wd2_f + fo, Warea + 2 * D * HD, D * HD);
          cvt(Wt2_f + fo, Warea + 3 * D * HD, D * HD);
          w1d = Warea; w1t = Warea + D * HD; w2d = Warea + 2 * D * HD;
          w2t = Warea + 3 * D * HD;
        }
        gemm8(DN, 1024, w1d, 2048, 1024, H1d, 2048, bd1 + n * D, 1, 0, 0,
              TN, w1t, H1t, bt1 + n * D);
        gemm8(H1d, 2048, w2d, 1024, 2048, Xf, 2048, bd2 + n * HD, 0, 1, 1,
              H1t, w2t, Xf + HD, bt2 + n * HD);
      }
    }

    // final head
    const unsigned short* Wo1p;
    if (planAll) {
      Wo1p = Wo1_b;
    } else {
      cvt(Wo1_f, Warea, HD * D);
      Wo1p = Warea;
    }
    gemm8(XN, 2048, Wo1p, 1024, 2048, Hfin, 1024, bo1, 1, 0, 0,
          nullptr, nullptr, nullptr, nullptr);
    final_matvec_kernel<<<8192, 256, 0, stream>>>(Hfin, Wo2_f, bo2,
                                                  (float*)d_out);
    return;
  }

  // ======================= legacy fallback path =======================
  const size_t PLB = R * D * 2;
  const size_t XFZ = R * D * 4;
  const size_t SLOT1 = DD * 2;
  const bool planAll = ws_size >= XFZ + 4 * PLB + WALL;
  const bool xIsF32 = planAll || ws_size >= XFZ + 4 * PLB + SLOT1;

  char* p = (char*)d_ws;
  float* Xf = nullptr;
  unsigned short* Xb = nullptr;
  if (xIsF32) { Xf = (float*)p; p += XFZ; } else { Xb = (unsigned short*)p; p += PLB; }
  unsigned short* XN = (unsigned short*)p; p += PLB;
  unsigned short* Qb = (unsigned short*)p; p += PLB;
  unsigned short* Kb = (unsigned short*)p; p += PLB;
  unsigned short* Vb = (unsigned short*)p; p += PLB;
  unsigned short* Warea = (unsigned short*)p;

  void* X = xIsF32 ? (void*)Xf : (void*)Xb;
  const int xres_mode = xIsF32 ? 1 : 2;
  unsigned short* H1 = Qb;
  unsigned short* DN = XN;
  unsigned short* TN = XN + R * HD;
  unsigned short* Hfin = Vb;

  unsigned short* Wq_b = Warea;
  unsigned short* Wk_b = Wq_b + 3 * DD;
  unsigned short* Wv_b = Wk_b + 3 * DD;
  unsigned short* Wd1_b = Wv_b + 3 * DD;
  unsigned short* Wd2_b = Wd1_b + 2 * D * HD;
  unsigned short* Wt1_b = Wd2_b + 2 * D * HD;
  unsigned short* Wt2_b = Wt1_b + 2 * D * HD;
  unsigned short* Wo1_b = Wt2_b + 2 * D * HD;
  if (planAll) {
    cvt(Wq_f, Wq_b, 3 * DD);
    cvt(Wk_f, Wk_b, 3 * DD);
    cvt(Wv_f, Wv_b, 3 * DD);
    cvt(Wd1_f, Wd1_b, 2 * D * HD);
    cvt(Wd2_f, Wd2_b, 2 * D * HD);
    cvt(Wt1_f, Wt1_b, 2 * D * HD);
    cvt(Wt2_f, Wt2_b, 2 * D * HD);
    cvt(Wo1_f, Wo1_b, HD * D);
  }
  auto wbf = [&](const float* src_base, unsigned short* pre_base, size_t off,
                 size_t cnt) -> const unsigned short* {
    if (planAll) return pre_base + off;
    cvt(src_base + off, Warea, (long)cnt);
    return Warea;
  };
  auto gemm = [&](const unsigned short* A, int lda, const unsigned short* B,
                  int N, int K, void* C, int ldc, const float* bias,
                  const void* res, int res_mode, int ldres, int relu, int of32) {
    dim3 grid(N / 128, 8192 / 128);
    gemm_bt_kernel<<<grid, dim3(256), 0, stream>>>(
        A, lda, B, K, C, ldc, bias, res, res_mode, ldres, relu, of32);
  };

  for (int n = 0; n < 3; ++n) {
    const void* lin = (n == 0) ? (const void*)x_in : (const void*)X;
    const int lin_bf16 = (n == 0) ? 0 : (xIsF32 ? 0 : 1);
    ln_kernel<2048><<<8192, 256, 0, stream>>>(lin, lin_bf16, 2048,
                                              aln_g + n * D, aln_b + n * D, XN, 2048);
    const size_t wo = (size_t)n * DD;
    gemm(XN, 2048, wbf(Wq_f, Wq_b, wo, DD), 2048, 2048, Qb, 2048,
         nullptr, nullptr, 0, 0, 0, 0);
    gemm(XN, 2048, wbf(Wk_f, Wk_b, wo, DD), 2048, 2048, Kb, 2048,
         nullptr, nullptr, 0, 0, 0, 0);
    gemm(XN, 2048, wbf(Wv_f, Wv_b, wo, DD), 2048, 2048, Vb, 2048,
         nullptr, nullptr, 0, 0, 0, 0);
    attn_glue_kernel<<<8192, 512, 0, stream>>>(
        Qb, Kb, Vb, 2048, (n == 0) ? (const void*)x_in : (const void*)X,
        (n == 0) ? 0 : (xIsF32 ? 0 : 1), X, xIsF32 ? 0 : 1,
        (n == 2 && xIsF32) ? XN : nullptr,
        nullptr, nullptr, nullptr, nullptr, nullptr, nullptr);

    if (n < 2) {
      const size_t fo = (size_t)n * D * HD;
      ln_kernel<1024><<<8192, 256, 0, stream>>>(X, !xIsF32, 2048,
                                                lnd_g + n * HD, lnd_b + n * HD, DN, 1024);
      const void* Xt = xIsF32 ? (const void*)(Xf + HD) : (const void*)(Xb + HD);
      ln_kernel<1024><<<8192, 256, 0, stream>>>(Xt, !xIsF32, 2048,
                                                lnt_g + n * HD, lnt_b + n * HD, TN, 1024);
      void* Xd2 = X;
      void* Xt2 = xIsF32 ? (void*)(Xf + HD) : (void*)(Xb + HD);
      gemm(DN, 1024, wbf(Wd1_f, Wd1_b, fo, D * HD), 2048, 1024, H1, 2048,
           bd1 + n * D, nullptr, 0, 0, 1, 0);
      gemm(H1, 2048, wbf(Wd2_f, Wd2_b, fo, D * HD), 1024, 2048, Xd2, 2048,
           bd2 + n * HD, Xd2, xres_mode, 2048, 0, xIsF32 ? 1 : 0);
      gemm(TN, 1024, wbf(Wt1_f, Wt1_b, fo, D * HD), 2048, 1024, H1, 2048,
           bt1 + n * D, nullptr, 0, 0, 1, 0);
      gemm(H1, 2048, wbf(Wt2_f, Wt2_b, fo, D * HD), 1024, 2048, Xt2, 2048,
           bt2 + n * HD, Xt2, xres_mode, 2048, 0, xIsF32 ? 1 : 0);
    }
  }

  const unsigned short* Afin = xIsF32 ? XN : Xb;
  gemm(Afin, 2048, wbf(Wo1_f, Wo1_b, 0, HD * D), 1024, 2048, Hfin, 1024,
       bo1, nullptr, 0, 0, 1, 0);
  final_matvec_kernel<<<8192, 256, 0, stream>>>(Hfin, Wo2_f, bo2, (float*)d_out);
}

// Round 11
// 1250.327 us; speedup vs baseline: 2.3342x; 1.0576x over previous
//
#include <hip/hip_runtime.h>
#include <stdint.h>

// ---------------------------------------------------------------------------
// PairwiseAttentionLinear — fp32 in/out on device.
// Round 11: gemm2b = 256x128 tile, BK=64, single-buffer 48KB LDS, 8 waves
// (4Mx2N, 64x64/wave -> acc=64 VGPR), __launch_bounds__(512,4) => 2 blocks/CU.
// Mechanism: cross-block overlap (m114) hides barrier/drain stalls that six
// intra-block schedule variants could not move at 1 block/CU. T1 swizzle
// REVERTED (r10: doubled FETCH, neutral time).
// ---------------------------------------------------------------------------

typedef __bf16 bf16x8 __attribute__((ext_vector_type(8)));
typedef float f32x4 __attribute__((ext_vector_type(4)));

static __device__ __forceinline__ float bf2f(unsigned short u) {
  unsigned int x = ((unsigned int)u) << 16;
  float f;
  __builtin_memcpy(&f, &x, 4);
  return f;
}
static __device__ __forceinline__ unsigned short f2bf(float f) {
  unsigned int x;
  __builtin_memcpy(&x, &f, 4);
  x += 0x7fffu + ((x >> 16) & 1u);  // RNE
  return (unsigned short)(x >> 16);
}

static __device__ __forceinline__ void gload_lds16(const void* g, void* l) {
  __builtin_amdgcn_global_load_lds(
      (const __attribute__((address_space(1))) unsigned int*)g,
      (__attribute__((address_space(3))) unsigned int*)l, 16, 0, 0);
}

__global__ __launch_bounds__(256) void cvt_kernel(
    const float* __restrict__ in, unsigned short* __restrict__ out, long n) {
  const long i = ((long)blockIdx.x * 256 + threadIdx.x) * 4;
  if (i + 3 < n) {
    float4 f = *(const float4*)(in + i);
    *(ushort4*)(out + i) = make_ushort4(f2bf(f.x), f2bf(f.y), f2bf(f.z), f2bf(f.w));
  }
}

// Multi-segment fp32->bf16 (segment lengths multiples of 1024).
#define MAXSEG 14
struct CvtArgs {
  const float* src[MAXSEG];
  unsigned short* dst[MAXSEG];
  long pfx[MAXSEG + 1];
  int ns;
};
__global__ __launch_bounds__(256) void cvt_multi_kernel(CvtArgs a) {
  const long i = ((long)blockIdx.x * 256 + threadIdx.x) * 4;
  int s = 0;
  while (s + 1 < a.ns && i >= a.pfx[s + 1]) ++s;
  const long off = i - a.pfx[s];
  float4 f = *(const float4*)(a.src[s] + off);
  *(ushort4*)(a.dst[s] + off) =
      make_ushort4(f2bf(f.x), f2bf(f.y), f2bf(f.z), f2bf(f.w));
}

// ---------------------------------------------------------------------------
#define BARRIER __builtin_amdgcn_s_barrier()
#define LGKM(N)                                                     \
  do {                                                              \
    asm volatile("s_waitcnt lgkmcnt(" #N ")" ::: "memory");         \
    __builtin_amdgcn_sched_barrier(0);                              \
  } while (0)
#define VMC(N)                                                      \
  do {                                                              \
    asm volatile("s_waitcnt vmcnt(" #N ")" ::: "memory");           \
    __builtin_amdgcn_sched_barrier(0);                              \
  } while (0)

// gemm2b: C[i,j] = act(sum_k A[i,k]*B[j,k] + bias[j]) [+C prior (resadd)]
// 256x128 tile, BK=64, 512 thr, 8 waves 4Mx2N (64x64 each). LDS 48KB single
// buffer: A[256][64] @0 (32KB) | B[128][64] @32768 (16KB). T2 swizzle
// byte ^= ((row&7)<<4) via pre-swizzled global src + swizzled ds_read.
// dual: blocks with bx >= gridDim.x/2 use second operand set.
__global__ __launch_bounds__(512, 4) void gemm2b_kernel(
    const unsigned short* __restrict__ A, int lda,
    const unsigned short* __restrict__ B, int K,
    void* __restrict__ Cp, int ldc, const float* __restrict__ bias,
    int relu, int out_f32, int resadd,
    const unsigned short* __restrict__ A2, const unsigned short* __restrict__ B2,
    void* __restrict__ C2p, const float* __restrict__ bias2, int dual) {
  __shared__ __align__(16) char smem[49152];

  const int tid = threadIdx.x;
  const int lane = tid & 63;
  const int w = tid >> 6;
  const int wm = w >> 1;  // 0..3
  const int wn = w & 1;   // 0..1
  const long brow = (long)blockIdx.y * 256;

  const unsigned short* Ap = A;
  const unsigned short* Bp = B;
  const float* bi = bias;
  void* Cq = Cp;
  long bcol;
  const int gx = (int)gridDim.x;
  const int bx = (int)blockIdx.x;
  if (dual && bx >= (gx >> 1)) {
    Ap = A2; Bp = B2; bi = bias2; Cq = C2p;
    bcol = (long)(bx - (gx >> 1)) * 128;
  } else {
    bcol = (long)bx * 128;
  }

  const int NT = K >> 6;  // K-tiles of 64

  // staging addressing (pre-swizzled source, linear LDS dest — rule #21)
  const int lrA = tid >> 3;                                    // row 0..63
  const int scb = ((tid & 7) * 16) ^ (((tid >> 3) & 7) << 4);  // pre-swz
  const unsigned wb = (unsigned)tid * 16;                      // linear dest
  const long ldab = (long)lda * 2;
  const long ldbb = (long)K * 2;
  const char* gA = (const char*)Ap + (brow + lrA) * ldab + scb;
  const char* gB = (const char*)Bp + (bcol + lrA) * ldbb + scb;
  const long a64 = 64 * ldab, a128 = 128 * ldab, a192 = 192 * ldab;
  const long b64 = 64 * ldbb;

#define STAGE(off)                                              \
  do {                                                          \
    gload_lds16(gA + (off), smem + (wb & ~1023u));              \
    gload_lds16(gA + a64 + (off), smem + 8192 + (wb & ~1023u)); \
    gload_lds16(gA + a128 + (off), smem + 16384 + (wb & ~1023u)); \
    gload_lds16(gA + a192 + (off), smem + 24576 + (wb & ~1023u)); \
    gload_lds16(gB + (off), smem + 32768 + (wb & ~1023u));      \
    gload_lds16(gB + b64 + (off), smem + 40960 + (wb & ~1023u)); \
  } while (0)

  f32x4 acc[4][4];
  const f32x4 fz = {0.f, 0.f, 0.f, 0.f};
#pragma unroll
  for (int m = 0; m < 4; ++m)
#pragma unroll
    for (int n = 0; n < 4; ++n) acc[m][n] = fz;

  const int frow = lane & 15;
  const int fkb = (lane >> 4) * 16;  // k-byte within 128B row
  const int fswz = (lane & 7) << 4;  // T2 read-side swizzle

#define RDA(dst, M, KK)                                                       \
  dst = *(const bf16x8*)(smem + (wm * 64 + (M) * 16 + frow) * 128 +           \
                         (((KK) * 64 + fkb) ^ fswz))
#define RDB(dst, N, KK)                                                       \
  dst = *(const bf16x8*)(smem + 32768 + (wn * 64 + (N) * 16 + frow) * 128 +   \
                         (((KK) * 64 + fkb) ^ fswz))

  // 16 MFMAs, one kk: per-acc reuse distance 16
#define MM16(A4, B4)                                                          \
  do {                                                                        \
    _Pragma("unroll") for (int mm = 0; mm < 4; ++mm)                          \
    _Pragma("unroll") for (int nn = 0; nn < 4; ++nn)                          \
        acc[mm][nn] = __builtin_amdgcn_mfma_f32_16x16x32_bf16(                \
            A4[mm], B4[nn], acc[mm][nn], 0, 0, 0);                            \
  } while (0)

  // prologue: stage tile 0 (single buffer)
  STAGE(0);
  long soff = 128;  // byte col-offset of tile t+1

  for (int t = 0; t < NT; ++t) {
    VMC(0);   // own stage loads landed
    BARRIER;  // ...for all waves -> tile t fully in LDS

    bf16x8 a0[4], b0[4];
    RDA(a0[0], 0, 0); RDA(a0[1], 1, 0); RDA(a0[2], 2, 0); RDA(a0[3], 3, 0);
    RDB(b0[0], 0, 0); RDB(b0[1], 1, 0); RDB(b0[2], 2, 0); RDB(b0[3], 3, 0);
    LGKM(0);
    __builtin_amdgcn_s_setprio(1);
    MM16(a0, b0);
    __builtin_amdgcn_s_setprio(0);
    __builtin_amdgcn_sched_barrier(0);

    bf16x8 a1[4], b1[4];
    RDA(a1[0], 0, 1); RDA(a1[1], 1, 1); RDA(a1[2], 2, 1); RDA(a1[3], 3, 1);
    RDB(b1[0], 0, 1); RDB(b1[1], 1, 1); RDB(b1[2], 2, 1); RDB(b1[3], 3, 1);
    LGKM(0);
    BARRIER;  // all waves done reading tile t -> overwrite safe
    if (t + 1 < NT) STAGE(soff);
    __builtin_amdgcn_s_setprio(1);
    MM16(a1, b1);
    __builtin_amdgcn_s_setprio(0);
    __builtin_amdgcn_sched_barrier(0);
    soff += 128;
  }

  // epilogue: C/D layout col=lane&15, row=(lane>>4)*4+reg [m89]
  const long rb0 = brow + wm * 64 + (lane >> 4) * 4;
  const long cb0 = bcol + wn * 64 + (lane & 15);
#pragma unroll
  for (int m = 0; m < 4; ++m) {
#pragma unroll
    for (int n = 0; n < 4; ++n) {
      const long col = cb0 + n * 16;
      const float bv = bi ? bi[col] : 0.f;
#pragma unroll
      for (int j = 0; j < 4; ++j) {
        const long r = rb0 + m * 16 + j;
        float v = acc[m][n][j] + bv;
        if (relu) v = fmaxf(v, 0.f);
        if (out_f32) {
          float* cp = (float*)Cq + r * (long)ldc + col;
          if (resadd) v += *cp;
          *cp = v;
        } else {
          ((unsigned short*)Cq)[r * (long)ldc + col] = f2bf(v);
        }
      }
    }
  }
#undef STAGE
#undef RDA
#undef RDB
#undef MM16
}

// ---------------------------------------------------------------------------
// Legacy 128x128 GEMM — fallback path only.
// ---------------------------------------------------------------------------
__global__ __launch_bounds__(256) void gemm_bt_kernel(
    const unsigned short* __restrict__ A, int lda,
    const unsigned short* __restrict__ B, int K,
    void* __restrict__ Cp, int ldc,
    const float* __restrict__ bias,
    const void* __restrict__ res, int res_mode, int ldres,
    int relu, int out_f32) {
  __shared__ __align__(16) unsigned short As[128 * 32];
  __shared__ __align__(16) unsigned short Bs[128 * 32];

  const int t = threadIdx.x;
  const int lane = t & 63;
  const int w = t >> 6;
  const int wr = (w >> 1) * 64;
  const int wc = (w & 1) * 64;
  const long brow = (long)blockIdx.y * 128;
  const long bcol = (long)blockIdx.x * 128;

  const int srow = lane >> 2;
  const int scol = (lane & 3) * 8;
  const unsigned short* Ab = A + (brow + w * 32 + srow) * (long)lda + scol;
  const unsigned short* Bb = B + (bcol + w * 32 + srow) * (long)K + scol;
  unsigned short* Asb = &As[(w * 32) * 32];
  unsigned short* Bsb = &Bs[(w * 32) * 32];

  f32x4 acc[4][4];
  const f32x4 fzero = {0.f, 0.f, 0.f, 0.f};
#pragma unroll
  for (int m = 0; m < 4; ++m)
#pragma unroll
    for (int n = 0; n < 4; ++n) acc[m][n] = fzero;

  const int fr = lane & 15;
  const int fk = (lane >> 4) * 8;

  for (int kt = 0; kt < K; kt += 32) {
    gload_lds16(Ab + kt, Asb);
    gload_lds16(Ab + 16 * (long)lda + kt, Asb + 16 * 32);
    gload_lds16(Bb + kt, Bsb);
    gload_lds16(Bb + 16 * (long)K + kt, Bsb + 16 * 32);
    __syncthreads();

    bf16x8 af[4], bfv[4];
#pragma unroll
    for (int m = 0; m < 4; ++m)
      af[m] = *(const bf16x8*)&As[(wr + m * 16 + fr) * 32 + fk];
#pragma unroll
    for (int n = 0; n < 4; ++n)
      bfv[n] = *(const bf16x8*)&Bs[(wc + n * 16 + fr) * 32 + fk];
#pragma unroll
    for (int m = 0; m < 4; ++m)
#pragma unroll
      for (int n = 0; n < 4; ++n)
        acc[m][n] = __builtin_amdgcn_mfma_f32_16x16x32_bf16(af[m], bfv[n],
                                                            acc[m][n], 0, 0, 0);
    __syncthreads();
  }

  const long rbase = brow + wr + (lane >> 4) * 4;
#pragma unroll
  for (int m = 0; m < 4; ++m) {
#pragma unroll
    for (int n = 0; n < 4; ++n) {
      const long col = bcol + wc + n * 16 + fr;
      const float bv = bias ? bias[col] : 0.f;
#pragma unroll
      for (int j = 0; j < 4; ++j) {
        const long r = rbase + m * 16 + j;
        float v = acc[m][n][j] + bv;
        if (relu) v = fmaxf(v, 0.f);
        if (res_mode == 1)
          v += ((const float*)res)[r * (long)ldres + col];
        else if (res_mode == 2)
          v += bf2f(((const unsigned short*)res)[r * (long)ldres + col]);
        if (out_f32)
          ((float*)Cp)[r * (long)ldc + col] = v;
        else
          ((unsigned short*)Cp)[r * (long)ldc + col] = f2bf(v);
      }
    }
  }
}

// ---------------------------------------------------------------------------
template <int L>
__global__ __launch_bounds__(256) void ln_kernel(
    const void* __restrict__ inp, int in_bf16, int ldin,
    const float* __restrict__ g, const float* __restrict__ b,
    unsigned short* __restrict__ outp, int ldout) {
  constexpr int VEC = L / 256;
  const long row = blockIdx.x;
  const int t = threadIdx.x;
  float v[VEC];
  if (in_bf16) {
    const unsigned short* p = (const unsigned short*)inp + row * (long)ldin + t * VEC;
#pragma unroll
    for (int i = 0; i < VEC; i += 4) {
      ushort4 u = *(const ushort4*)(p + i);
      v[i] = bf2f(u.x); v[i + 1] = bf2f(u.y); v[i + 2] = bf2f(u.z); v[i + 3] = bf2f(u.w);
    }
  } else {
    const float* p = (const float*)inp + row * (long)ldin + t * VEC;
#pragma unroll
    for (int i = 0; i < VEC; i += 4) {
      float4 f = *(const float4*)(p + i);
      v[i] = f.x; v[i + 1] = f.y; v[i + 2] = f.z; v[i + 3] = f.w;
    }
  }
  float s = 0.f, sq = 0.f;
#pragma unroll
  for (int i = 0; i < VEC; ++i) { s += v[i]; sq += v[i] * v[i]; }
#pragma unroll
  for (int off = 32; off; off >>= 1) {
    s += __shfl_xor(s, off, 64);
    sq += __shfl_xor(sq, off, 64);
  }
  __shared__ float red[8];
  if ((t & 63) == 0) { red[t >> 6] = s; red[4 + (t >> 6)] = sq; }
  __syncthreads();
  s = red[0] + red[1] + red[2] + red[3];
  sq = red[4] + red[5] + red[6] + red[7];
  const float mean = s * (1.f / L);
  const float var = sq * (1.f / L) - mean * mean;
  const float rstd = rsqrtf(var + 1e-6f);
  unsigned short* op = outp + row * (long)ldout + t * VEC;
  const float* gp = g + t * VEC;
  const float* bp = b + t * VEC;
#pragma unroll
  for (int i = 0; i < VEC; i += 4) {
    float4 gg = *(const float4*)(gp + i);
    float4 bb = *(const float4*)(bp + i);
    *(ushort4*)(op + i) = make_ushort4(
        f2bf((v[i + 0] - mean) * rstd * gg.x + bb.x),
        f2bf((v[i + 1] - mean) * rstd * gg.y + bb.y),
        f2bf((v[i + 2] - mean) * rstd * gg.z + bb.z),
        f2bf((v[i + 3] - mean) * rstd * gg.w + bb.w));
  }
}

// ---------------------------------------------------------------------------
// Pairwise attention glue + optional fused d/t LayerNorms. Xout nullable.
// ---------------------------------------------------------------------------
__global__ __launch_bounds__(512) void attn_glue_kernel(
    const unsigned short* __restrict__ Q, const unsigned short* __restrict__ Kq,
    const unsigned short* __restrict__ V, int ld, const void* __restrict__ Xres,
    int res_bf16, void* __restrict__ Xout, int out_bf16,
    unsigned short* __restrict__ Xout_bf,
    unsigned short* __restrict__ DNp, unsigned short* __restrict__ TNp,
    const float* __restrict__ lnd_g, const float* __restrict__ lnd_b,
    const float* __restrict__ lnt_g, const float* __restrict__ lnt_b) {
  const long row = blockIdx.x;
  const int h = threadIdx.x >> 6;
  const int lane = threadIdx.x & 63;
  const long qbase = row * (long)ld + h * 256;
  const long xbase = row * 2048 + h * 256;
  const int d = lane * 2;

  ushort2 q0 = *(const ushort2*)&Q[qbase + d];
  ushort2 q1 = *(const ushort2*)&Q[qbase + 128 + d];
  ushort2 k0 = *(const ushort2*)&Kq[qbase + d];
  ushort2 k1 = *(const ushort2*)&Kq[qbase + 128 + d];
  ushort2 v0 = *(const ushort2*)&V[qbase + d];
  ushort2 v1 = *(const ushort2*)&V[qbase + 128 + d];

  const float q0x = bf2f(q0.x), q0y = bf2f(q0.y);
  const float q1x = bf2f(q1.x), q1y = bf2f(q1.y);
  const float k0x = bf2f(k0.x), k0y = bf2f(k0.y);
  const float k1x = bf2f(k1.x), k1y = bf2f(k1.y);

  float s00 = q0x * k0x + q0y * k0y;
  float s01 = q0x * k1x + q0y * k1y;
  float s10 = q1x * k0x + q1y * k0y;
  float s11 = q1x * k1x + q1y * k1y;
#pragma unroll
  for (int off = 32; off; off >>= 1) {
    s00 += __shfl_xor(s00, off, 64);
    s01 += __shfl_xor(s01, off, 64);
    s10 += __shfl_xor(s10, off, 64);
    s11 += __shfl_xor(s11, off, 64);
  }
  const float SC = 0.088388347648318447f;  // 1/sqrt(128)
  s00 *= SC; s01 *= SC; s10 *= SC; s11 *= SC;
  const float m0 = fmaxf(s00, s01), m1 = fmaxf(s10, s11);
  const float e00 = __expf(s00 - m0), e01 = __expf(s01 - m0);
  const float e10 = __expf(s10 - m1), e11 = __expf(s11 - m1);
  const float i0 = 1.f / (e00 + e01), i1 = 1.f / (e10 + e11);
  const float a00 = e00 * i0, a01 = e01 * i0;
  const float a10 = e10 * i1, a11 = e11 * i1;

  const float v0x = bf2f(v0.x), v0y = bf2f(v0.y);
  const float v1x = bf2f(v1.x), v1y = bf2f(v1.y);
  float o0x = a00 * v0x + a01 * v1x, o0y = a00 * v0y + a01 * v1y;
  float o1x = a10 * v0x + a11 * v1x, o1y = a10 * v0y + a11 * v1y;

  if (res_bf16) {
    const unsigned short* xr = (const unsigned short*)Xres + xbase;
    ushort2 ra = *(const ushort2*)&xr[d];
    ushort2 rb = *(const ushort2*)&xr[128 + d];
    o0x += bf2f(ra.x); o0y += bf2f(ra.y); o1x += bf2f(rb.x); o1y += bf2f(rb.y);
  } else {
    const float* xr = (const float*)Xres + xbase;
    float2 ra = *(const float2*)&xr[d];
    float2 rb = *(const float2*)&xr[128 + d];
    o0x += ra.x; o0y += ra.y; o1x += rb.x; o1y += rb.y;
  }
  if (Xout) {
    if (out_bf16) {
      unsigned short* xo = (unsigned short*)Xout + xbase;
      *(ushort2*)&xo[d] = make_ushort2(f2bf(o0x), f2bf(o0y));
      *(ushort2*)&xo[128 + d] = make_ushort2(f2bf(o1x), f2bf(o1y));
    } else {
      float* xo = (float*)Xout + xbase;
      *(float2*)&xo[d] = make_float2(o0x, o0y);
      *(float2*)&xo[128 + d] = make_float2(o1x, o1y);
    }
  }
  if (Xout_bf) {
    unsigned short* xb = Xout_bf + xbase;
    *(ushort2*)&xb[d] = make_ushort2(f2bf(o0x), f2bf(o0y));
    *(ushort2*)&xb[128 + d] = make_ushort2(f2bf(o1x), f2bf(o1y));
  }

  if (DNp) {
    float s4 = o0x + o0y + o1x + o1y;
    float q4 = o0x * o0x + o0y * o0y + o1x * o1x + o1y * o1y;
#pragma unroll
    for (int off = 32; off; off >>= 1) {
      s4 += __shfl_xor(s4, off, 64);
      q4 += __shfl_xor(q4, off, 64);
    }
    __shared__ float redS[8], redQ[8];
    if (lane == 0) { redS[h] = s4; redQ[h] = q4; }
    __syncthreads();
    const int b4 = (h >> 2) * 4;
    const float S = redS[b4] + redS[b4 + 1] + redS[b4 + 2] + redS[b4 + 3];
    const float Qs = redQ[b4] + redQ[b4 + 1] + redQ[b4 + 2] + redQ[b4 + 3];
    const float mean = S * (1.f / 1024.f);
    const float var = Qs * (1.f / 1024.f) - mean * mean;
    const float rstd = rsqrtf(var + 1e-6f);
    const float* gp = (h < 4) ? lnd_g : lnt_g;
    const float* bp = (h < 4) ? lnd_b : lnt_b;
    unsigned short* dst = ((h < 4) ? DNp : TNp) + row * 1024;
    const int hc = (h & 3) * 256 + d;
    float2 g0 = *(const float2*)&gp[hc];
    float2 b0 = *(const float2*)&bp[hc];
    *(ushort2*)&dst[hc] = make_ushort2(f2bf((o0x - mean) * rstd * g0.x + b0.x),
                                       f2bf((o0y - mean) * rstd * g0.y + b0.y));
    float2 g1 = *(const float2*)&gp[hc + 128];
    float2 b1 = *(const float2*)&bp[hc + 128];
    *(ushort2*)&dst[hc + 128] =
        make_ushort2(f2bf((o1x - mean) * rstd * g1.x + b1.x),
                     f2bf((o1y - mean) * rstd * g1.y + b1.y));
  }
}

__global__ __launch_bounds__(256) void final_matvec_kernel(
    const unsigned short* __restrict__ Hm, const float* __restrict__ wv,
    const float* __restrict__ b2, float* __restrict__ outp) {
  const long row = blockIdx.x;
  const int t = threadIdx.x;
  ushort4 hv = *(const ushort4*)&Hm[row * 1024 + t * 4];
  float4 wq = *(const float4*)&wv[t * 4];
  float s = bf2f(hv.x) * wq.x + bf2f(hv.y) * wq.y +
            bf2f(hv.z) * wq.z + bf2f(hv.w) * wq.w;
#pragma unroll
  for (int off = 32; off; off >>= 1) s += __shfl_xor(s, off, 64);
  __shared__ float red[4];
  if ((t & 63) == 0) red[t >> 6] = s;
  __syncthreads();
  if (t == 0) outp[row] = red[0] + red[1] + red[2] + red[3] + b2[0];
}

// ---------------------------------------------------------------------------
extern "C" void kernel_launch(void* const* d_in, const int* in_sizes, int n_in,
                              void* d_out, int out_size, void* d_ws,
                              size_t ws_size, hipStream_t stream) {
  const float* x_in = (const float*)d_in[0];
  const float* aln_g = (const float*)d_in[1];
  const float* aln_b = (const float*)d_in[2];
  const float* Wq_f = (const float*)d_in[3];
  const float* Wk_f = (const float*)d_in[4];
  const float* Wv_f = (const float*)d_in[5];
  const float* lnd_g = (const float*)d_in[6];
  const float* lnd_b = (const float*)d_in[7];
  const float* lnt_g = (const float*)d_in[8];
  const float* lnt_b = (const float*)d_in[9];
  const float* Wd1_f = (const float*)d_in[10];
  const float* bd1 = (const float*)d_in[11];
  const float* Wd2_f = (const float*)d_in[12];
  const float* bd2 = (const float*)d_in[13];
  const float* Wt1_f = (const float*)d_in[14];
  const float* bt1 = (const float*)d_in[15];
  const float* Wt2_f = (const float*)d_in[16];
  const float* bt2 = (const float*)d_in[17];
  const float* Wo1_f = (const float*)d_in[18];
  const float* bo1 = (const float*)d_in[19];
  const float* Wo2_f = (const float*)d_in[20];
  const float* bo2 = (const float*)d_in[21];

  const size_t R = 8192, D = 2048, HD = 1024;
  const size_t DD = D * D;
  const size_t WALL = (3 * 3 * DD + 4 * 2 * D * HD + HD * D) * 2;  // 108 MiB
  const size_t SLOT = 3 * DD * 2;                                  // 24 MiB
  const size_t ACT = R * D * 4 + R * D * 2 + R * 6144 * 2;         // 192 MiB

  auto cvt = [&](const float* src, unsigned short* dst, long n) {
    cvt_kernel<<<dim3((unsigned)(n / 1024)), dim3(256), 0, stream>>>(src, dst, n);
  };

  if (ws_size >= ACT + SLOT) {
    // ===================== fast path =====================
    const bool planAll = ws_size >= ACT + WALL;

    char* p = (char*)d_ws;
    float* Xf = (float*)p; p += R * D * 4;
    unsigned short* XN = (unsigned short*)p; p += R * D * 2;
    unsigned short* QKVb = (unsigned short*)p; p += R * 6144 * 2;
    unsigned short* Warea = (unsigned short*)p;

    unsigned short* H1d = QKVb;
    unsigned short* H1t = QKVb + R * 2048;
    unsigned short* Hfin = QKVb + R * 4096;
    unsigned short* DN = XN;
    unsigned short* TN = XN + R * HD;

    unsigned short* Wqkv_b = Warea;
    unsigned short* Wd1_b = Wqkv_b + 9 * DD;
    unsigned short* Wt1_b = Wd1_b + 2 * D * HD;
    unsigned short* Wd2_b = Wt1_b + 2 * D * HD;
    unsigned short* Wt2_b = Wd2_b + 2 * D * HD;
    unsigned short* Wo1_b = Wt2_b + 2 * D * HD;
    if (planAll) {
      CvtArgs ca;
      int s = 0;
      long pfx = 0;
      auto add = [&](const float* src, unsigned short* dst, long n) {
        ca.src[s] = src; ca.dst[s] = dst; ca.pfx[s] = pfx; pfx += n; ++s;
      };
      for (int n = 0; n < 3; ++n) {
        add(Wq_f + n * DD, Wqkv_b + n * 3 * DD + 0 * DD, (long)DD);
        add(Wk_f + n * DD, Wqkv_b + n * 3 * DD + 1 * DD, (long)DD);
        add(Wv_f + n * DD, Wqkv_b + n * 3 * DD + 2 * DD, (long)DD);
      }
      add(Wd1_f, Wd1_b, (long)(2 * D * HD));
      add(Wt1_f, Wt1_b, (long)(2 * D * HD));
      add(Wd2_f, Wd2_b, (long)(2 * D * HD));
      add(Wt2_f, Wt2_b, (long)(2 * D * HD));
      add(Wo1_f, Wo1_b, (long)(HD * D));
      ca.pfx[s] = pfx;
      ca.ns = s;
      cvt_multi_kernel<<<dim3((unsigned)(pfx / 1024)), dim3(256), 0, stream>>>(ca);
    }

    auto gemm = [&](const unsigned short* A, int lda, const unsigned short* B,
                    int N, int K, void* C, int ldc, const float* bias,
                    int relu, int of32, int resadd, const unsigned short* A2,
                    const unsigned short* B2, void* C2, const float* bias2) {
      const int dual = (A2 != nullptr);
      dim3 grid((dual ? 2 : 1) * (N / 128), 32);
      gemm2b_kernel<<<grid, dim3(512), 0, stream>>>(
          A, lda, B, K, C, ldc, bias, relu, of32, resadd, A2, B2, C2, bias2,
          dual);
    };

    for (int n = 0; n < 3; ++n) {
      ln_kernel<2048><<<8192, 256, 0, stream>>>(
          (n == 0) ? (const void*)x_in : (const void*)Xf, 0, 2048,
          aln_g + n * D, aln_b + n * D, XN, 2048);
      const unsigned short* Wqkv;
      if (planAll) {
        Wqkv = Wqkv_b + (size_t)n * 3 * DD;
      } else {
        cvt(Wq_f + n * DD, Warea + 0 * DD, DD);
        cvt(Wk_f + n * DD, Warea + 1 * DD, DD);
        cvt(Wv_f + n * DD, Warea + 2 * DD, DD);
        Wqkv = Warea;
      }
      gemm(XN, 2048, Wqkv, 6144, 2048, QKVb, 6144, nullptr, 0, 0, 0,
           nullptr, nullptr, nullptr, nullptr);
      attn_glue_kernel<<<8192, 512, 0, stream>>>(
          QKVb, QKVb + 2048, QKVb + 4096, 6144,
          (n == 0) ? (const void*)x_in : (const void*)Xf, 0,
          (n < 2) ? (void*)Xf : nullptr, 0,
          (n == 2) ? XN : nullptr,
          (n < 2) ? DN : nullptr, (n < 2) ? TN : nullptr,
          (n < 2) ? lnd_g + n * HD : nullptr, (n < 2) ? lnd_b + n * HD : nullptr,
          (n < 2) ? lnt_g + n * HD : nullptr, (n < 2) ? lnt_b + n * HD : nullptr);

      if (n < 2) {
        const size_t fo = (size_t)n * D * HD;
        const unsigned short *w1d, *w1t, *w2d, *w2t;
        if (planAll) {
          w1d = Wd1_b + fo; w1t = Wt1_b + fo; w2d = Wd2_b + fo; w2t = Wt2_b + fo;
        } else {
          cvt(Wd1_f + fo, Warea + 0 * D * HD, D * HD);
          cvt(Wt1_f + fo, Warea + 1 * D * HD, D * HD);
          cvt(Wd2_f + fo, Warea + 2 * D * HD, D * HD);
          cvt(Wt2_f + fo, Warea + 3 * D * HD, D * HD);
          w1d = Warea; w1t = Warea + D * HD; w2d = Warea + 2 * D * HD;
          w2t = Warea + 3 * D * HD;
        }
        gemm(DN, 1024, w1d, 2048, 1024, H1d, 2048, bd1 + n * D, 1, 0, 0,
             TN, w1t, H1t, bt1 + n * D);
        gemm(H1d, 2048, w2d, 1024, 2048, Xf, 2048, bd2 + n * HD, 0, 1, 1,
             H1t, w2t, Xf + HD, bt2 + n * HD);
      }
    }

    // final head
    const unsigned short* Wo1p;
    if (planAll) {
      Wo1p = Wo1_b;
    } else {
      cvt(Wo1_f, Warea, HD * D);
      Wo1p = Warea;
    }
    gemm(XN, 2048, Wo1p, 1024, 2048, Hfin, 1024, bo1, 1, 0, 0,
         nullptr, nullptr, nullptr, nullptr);
    final_matvec_kernel<<<8192, 256, 0, stream>>>(Hfin, Wo2_f, bo2,
                                                  (float*)d_out);
    return;
  }

  // ======================= legacy fallback path =======================
  const size_t PLB = R * D * 2;
  const size_t XFZ = R * D * 4;
  const size_t SLOT1 = DD * 2;
  const bool planAll = ws_size >= XFZ + 4 * PLB + WALL;
  const bool xIsF32 = planAll || ws_size >= XFZ + 4 * PLB + SLOT1;

  char* p = (char*)d_ws;
  float* Xf = nullptr;
  unsigned short* Xb = nullptr;
  if (xIsF32) { Xf = (float*)p; p += XFZ; } else { Xb = (unsigned short*)p; p += PLB; }
  unsigned short* XN = (unsigned short*)p; p += PLB;
  unsigned short* Qb = (unsigned short*)p; p += PLB;
  unsigned short* Kb = (unsigned short*)p; p += PLB;
  unsigned short* Vb = (unsigned short*)p; p += PLB;
  unsigned short* Warea = (unsigned short*)p;

  void* X = xIsF32 ? (void*)Xf : (void*)Xb;
  const int xres_mode = xIsF32 ? 1 : 2;
  unsigned short* H1 = Qb;
  unsigned short* DN = XN;
  unsigned short* TN = XN + R * HD;
  unsigned short* Hfin = Vb;

  unsigned short* Wq_b = Warea;
  unsigned short* Wk_b = Wq_b + 3 * DD;
  unsigned short* Wv_b = Wk_b + 3 * DD;
  unsigned short* Wd1_b = Wv_b + 3 * DD;
  unsigned short* Wd2_b = Wd1_b + 2 * D * HD;
  unsigned short* Wt1_b = Wd2_b + 2 * D * HD;
  unsigned short* Wt2_b = Wt1_b + 2 * D * HD;
  unsigned short* Wo1_b = Wt2_b + 2 * D * HD;
  if (planAll) {
    cvt(Wq_f, Wq_b, 3 * DD);
    cvt(Wk_f, Wk_b, 3 * DD);
    cvt(Wv_f, Wv_b, 3 * DD);
    cvt(Wd1_f, Wd1_b, 2 * D * HD);
    cvt(Wd2_f, Wd2_b, 2 * D * HD);
    cvt(Wt1_f, Wt1_b, 2 * D * HD);
    cvt(Wt2_f, Wt2_b, 2 * D * HD);
    cvt(Wo1_f, Wo1_b, HD * D);
  }
  auto wbf = [&](const float* src_base, unsigned short* pre_base, size_t off,
                 size_t cnt) -> const unsigned short* {
    if (planAll) return pre_base + off;
    cvt(src_base + off, Warea, (long)cnt);
    return Warea;
  };
  auto gemm = [&](const unsigned short* A, int lda, const unsigned short* B,
                  int N, int K, void* C, int ldc, const float* bias,
                  const void* res, int res_mode, int ldres, int relu, int of32) {
    dim3 grid(N / 128, 8192 / 128);
    gemm_bt_kernel<<<grid, dim3(256), 0, stream>>>(
        A, lda, B, K, C, ldc, bias, res, res_mode, ldres, relu, of32);
  };

  for (int n = 0; n < 3; ++n) {
    const void* lin = (n == 0) ? (const void*)x_in : (const void*)X;
    const int lin_bf16 = (n == 0) ? 0 : (xIsF32 ? 0 : 1);
    ln_kernel<2048><<<8192, 256, 0, stream>>>(lin, lin_bf16, 2048,
                                              aln_g + n * D, aln_b + n * D, XN, 2048);
    const size_t wo = (size_t)n * DD;
    gemm(XN, 2048, wbf(Wq_f, Wq_b, wo, DD), 2048, 2048, Qb, 2048,
         nullptr, nullptr, 0, 0, 0, 0);
    gemm(XN, 2048, wbf(Wk_f, Wk_b, wo, DD), 2048, 2048, Kb, 2048,
         nullptr, nullptr, 0, 0, 0, 0);
    gemm(XN, 2048, wbf(Wv_f, Wv_b, wo, DD), 2048, 2048, Vb, 2048,
         nullptr, nullptr, 0, 0, 0, 0);
    attn_glue_kernel<<<8192, 512, 0, stream>>>(
        Qb, Kb, Vb, 2048, (n == 0) ? (const void*)x_in : (const void*)X,
        (n == 0) ? 0 : (xIsF32 ? 0 : 1), X, xIsF32 ? 0 : 1,
        (n == 2 && xIsF32) ? XN : nullptr,
        nullptr, nullptr, nullptr, nullptr, nullptr, nullptr);

    if (n < 2) {
      const size_t fo = (size_t)n * D * HD;
      ln_kernel<1024><<<8192, 256, 0, stream>>>(X, !xIsF32, 2048,
                                                lnd_g + n * HD, lnd_b + n * HD, DN, 1024);
      const void* Xt = xIsF32 ? (const void*)(Xf + HD) : (const void*)(Xb + HD);
      ln_kernel<1024><<<8192, 256, 0, stream>>>(Xt, !xIsF32, 2048,
                                                lnt_g + n * HD, lnt_b + n * HD, TN, 1024);
      void* Xd2 = X;
      void* Xt2 = xIsF32 ? (void*)(Xf + HD) : (void*)(Xb + HD);
      gemm(DN, 1024, wbf(Wd1_f, Wd1_b, fo, D * HD), 2048, 1024, H1, 2048,
           bd1 + n * D, nullptr, 0, 0, 1, 0);
      gemm(H1, 2048, wbf(Wd2_f, Wd2_b, fo, D * HD), 1024, 2048, Xd2, 2048,
           bd2 + n * HD, Xd2, xres_mode, 2048, 0, xIsF32 ? 1 : 0);
      gemm(TN, 1024, wbf(Wt1_f, Wt1_b, fo, D * HD), 2048, 1024, H1, 2048,
           bt1 + n * D, nullptr, 0, 0, 1, 0);
      gemm(H1, 2048, wbf(Wt2_f, Wt2_b, fo, D * HD), 1024, 2048, Xt2, 2048,
           bt2 + n * HD, Xt2, xres_mode, 2048, 0, xIsF32 ? 1 : 0);
    }
  }

  const unsigned short* Afin = xIsF32 ? XN : Xb;
  gemm(Afin, 2048, wbf(Wo1_f, Wo1_b, 0, HD * D), 1024, 2048, Hfin, 1024,
       bo1, nullptr, 0, 0, 1, 0);
  final_matvec_kernel<<<8192, 256, 0, stream>>>(Hfin, Wo2_f, bo2, (float*)d_out);
}